// Round 10
// baseline (1052.503 us; speedup 1.0000x reference)
//
#include <hip/hip_runtime.h>
#include <hip/hip_bf16.h>

#define CONCAT_F 1137
#define CONCAT_P 1152  // padded to multiple of 32 for bf16 MFMA GEMM
#define PROT_K 979
#define PROT_P 992     // 979 padded to 31*32

typedef __attribute__((ext_vector_type(8))) short bf16x8;
typedef __attribute__((ext_vector_type(4))) float f32x4;

static __device__ __forceinline__ float bfu2f(unsigned short u) {
  return __uint_as_float(((unsigned)u) << 16);
}
static __device__ __forceinline__ unsigned short f2bfu(float v) {
  __hip_bfloat16 t = __float2bfloat16(v);
  unsigned short u;
  __builtin_memcpy(&u, &t, 2);
  return u;
}

// accumulate a bf16x4 row chunk (uint2) into 4 floats
#define ACC4(A0, A1, A2, A3, U)        \
  {                                    \
    A0 += bfu2f((U).x & 0xffffu);      \
    A1 += bfu2f((U).x >> 16);          \
    A2 += bfu2f((U).y & 0xffffu);      \
    A3 += bfu2f((U).y >> 16);          \
  }

// ================= bucketed CSR build =================
// bucket = dst >> 10 (1024 nodes/bucket); 8 partition labels (blockIdx&7).
__global__ void k_bcount(const int* __restrict__ dst, int* __restrict__ bkt, int E) {
  int e = blockIdx.x * blockDim.x + threadIdx.x;
  if (e < E) atomicAdd(&bkt[(dst[e] >> 10) * 8 + (blockIdx.x & 7)], 1);
}

// exclusive scan of bkt[0..total) in place; total <= 4096; 1024 threads
__global__ void k_bscan(int* __restrict__ bkt, int total) {
  __shared__ int a[1024], b_[1024];
  int t = threadIdx.x;
  int base = t * 4;
  int v0 = 0, v1 = 0, v2 = 0, v3 = 0;
  if (base + 0 < total) v0 = bkt[base + 0];
  if (base + 1 < total) v1 = bkt[base + 1];
  if (base + 2 < total) v2 = bkt[base + 2];
  if (base + 3 < total) v3 = bkt[base + 3];
  a[t] = v0 + v1 + v2 + v3;
  __syncthreads();
  int* s = a;
  int* d = b_;
  for (int off = 1; off < 1024; off <<= 1) {
    d[t] = s[t] + ((t >= off) ? s[t - off] : 0);
    __syncthreads();
    int* tmp = s;
    s = d;
    d = tmp;
  }
  int run = (t == 0) ? 0 : s[t - 1];
  if (base + 0 < total) { bkt[base + 0] = run; run += v0; }
  if (base + 1 < total) { bkt[base + 1] = run; run += v1; }
  if (base + 2 < total) { bkt[base + 2] = run; run += v2; }
  if (base + 3 < total) { bkt[base + 3] = run; run += v3; }
}

// scatter (src,dst) pairs into bucket-major regions (label-partitioned)
__global__ void k_bscatter(const int* __restrict__ src, const int* __restrict__ dst,
                           int* __restrict__ bkt, int2* __restrict__ pairs, int E) {
  int e = blockIdx.x * blockDim.x + threadIdx.x;
  if (e < E) {
    int d = dst[e];
    int pos = atomicAdd(&bkt[(d >> 10) * 8 + (blockIdx.x & 7)], 1);
    pairs[pos] = make_int2(src[e], d);
  }
}

// region of bucket b (post-bump): [bkt[b*8-1] or 0, bkt[b*8+7])
// per-bucket dst counting into rs — all atomics in a 4KB window
__global__ void k_pcount(const int2* __restrict__ pairs, const int* __restrict__ bkt,
                         int* __restrict__ rs) {
  int b = blockIdx.x;
  int start = (b == 0) ? 0 : bkt[b * 8 - 1];
  int end = bkt[b * 8 + 7];
  for (int e = start + threadIdx.x; e < end; e += blockDim.x)
    atomicAdd(&rs[pairs[e].y], 1);
}

// per-bucket final scatter: csr window 16KB, rs window 4KB (single-XCD-hot)
__global__ void k_scatter2(const int2* __restrict__ pairs, const int* __restrict__ bkt,
                           int* __restrict__ rs, int* __restrict__ csr) {
  int b = blockIdx.x;
  int start = (b == 0) ? 0 : bkt[b * 8 - 1];
  int end = bkt[b * 8 + 7];
  for (int e = start + threadIdx.x; e < end; e += blockDim.x) {
    int2 p = pairs[e];
    int pos = atomicAdd(&rs[p.y], 1);
    csr[pos] = p.x;
  }
}

__global__ void k_disk(const int* __restrict__ cnt, float* __restrict__ dis, int n) {
  int i = blockIdx.x * blockDim.x + threadIdx.x;
  if (i < n) dis[i] = rsqrtf(1.0f + (float)cnt[i]);  // self-loop included
}

__global__ void k_scan_p1(const int* __restrict__ cnt, int* __restrict__ part, int n) {
  __shared__ int red[256];
  int tid = threadIdx.x;
  long base = (long)blockIdx.x * 1024 + tid * 4;
  int s = 0;
#pragma unroll
  for (int i = 0; i < 4; ++i) {
    long j = base + i;
    if (j < n) s += cnt[j];
  }
  red[tid] = s;
  __syncthreads();
  for (int off = 128; off; off >>= 1) {
    if (tid < off) red[tid] += red[tid + off];
    __syncthreads();
  }
  if (tid == 0) part[blockIdx.x] = red[0];
}

__global__ void k_scan_p2(int* __restrict__ part, int nb) {
  __shared__ int a[1024], b_[1024];
  int t = threadIdx.x;
  a[t] = (t < nb) ? part[t] : 0;
  __syncthreads();
  int* s = a;
  int* d = b_;
  for (int off = 1; off < 1024; off <<= 1) {
    d[t] = s[t] + ((t >= off) ? s[t - off] : 0);
    __syncthreads();
    int* tmp = s;
    s = d;
    d = tmp;
  }
  if (t < nb) part[t] = (t == 0) ? 0 : s[t - 1];  // exclusive
}

__global__ void k_scan_p3(int* __restrict__ rs, const int* __restrict__ part, int n) {
  __shared__ int a[256], b_[256];
  int tid = threadIdx.x;
  long base = (long)blockIdx.x * 1024 + tid * 4;
  int v[4];
#pragma unroll
  for (int i = 0; i < 4; ++i) {
    long j = base + i;
    v[i] = (j < n) ? rs[j] : 0;
  }
  a[tid] = v[0] + v[1] + v[2] + v[3];
  __syncthreads();
  int* s = a;
  int* d = b_;
  for (int off = 1; off < 256; off <<= 1) {
    d[tid] = s[tid] + ((tid >= off) ? s[tid - off] : 0);
    __syncthreads();
    int* t2 = s;
    s = d;
    d = t2;
  }
  int run = part[blockIdx.x] + ((tid == 0) ? 0 : s[tid - 1]);
#pragma unroll
  for (int i = 0; i < 4; ++i) {
    long j = base + i;
    if (j < n) {
      rs[j] = run;
      run += v[i];
    }
  }
}

// ====== GCN layer-1 matmul: M = dis*(X@W), f32 in, bf16 out (K=30) =========
template <int K, bool ACT>
__global__ __launch_bounds__(256) void k_mm(const void* __restrict__ Xv,
                                            const float* __restrict__ W,
                                            const float* __restrict__ bprev,
                                            const float* __restrict__ dis,
                                            unsigned short* __restrict__ M, int n) {
  __shared__ __align__(16) float hT[K][68];
  __shared__ __align__(16) float Ws[K * 64];
  __shared__ float disS[64];
  int tid = threadIdx.x;
  int rb = blockIdx.x * 64;
  for (int j = tid; j < K * 16; j += 256) ((float4*)Ws)[j] = ((const float4*)W)[j];
  if (tid < 64) disS[tid] = (rb + tid < n) ? dis[rb + tid] : 0.0f;
  __syncthreads();
  if constexpr (ACT) {
    const unsigned short* X = (const unsigned short*)Xv;
    int k = tid & 63;
    float bk = bprev[k];
#pragma unroll
    for (int r = tid >> 6; r < 64; r += 4) {
      float h = 0.0f;
      if (rb + r < n) {
        float raw = bfu2f(X[(long)(rb + r) * 64 + k]);
        h = fmaxf(fmaf(raw, disS[r], bk), 0.0f);
      }
      hT[k][r] = h;
    }
  } else {
    const float* X = (const float*)Xv;
    for (int idx = tid; idx < 64 * K; idx += 256) {
      int r = idx / K, k = idx - r * K;
      hT[k][r] = (rb + r < n) ? X[(long)(rb + r) * K + k] : 0.0f;
    }
  }
  __syncthreads();
  int rt = (tid & 15) * 4;
  int ct = (tid >> 4) * 4;
  float acc[4][4] = {};
#pragma unroll 5
  for (int k = 0; k < K; ++k) {
    float4 xr = *(const float4*)&hT[k][rt];
    float4 wr = *(const float4*)&Ws[k * 64 + ct];
    float xa[4] = {xr.x, xr.y, xr.z, xr.w};
    float wa[4] = {wr.x, wr.y, wr.z, wr.w};
#pragma unroll
    for (int i = 0; i < 4; ++i)
#pragma unroll
      for (int j = 0; j < 4; ++j) acc[i][j] = fmaf(xa[i], wa[j], acc[i][j]);
  }
#pragma unroll
  for (int i = 0; i < 4; ++i) {
    int row = rb + rt + i;
    if (row >= n) break;
    float dv = disS[rt + i];
    ushort4 pk;
    pk.x = f2bfu(acc[i][0] * dv);
    pk.y = f2bfu(acc[i][1] * dv);
    pk.z = f2bfu(acc[i][2] * dv);
    pk.w = f2bfu(acc[i][3] * dv);
    *(ushort4*)&M[(long)row * 64 + ct] = pk;
  }
}

// ---- 4-edge-unrolled row aggregation body (16 lanes x uint2 per row) -------
static __device__ __forceinline__ void gather_rows(
    const int* __restrict__ rs, const int* __restrict__ csr,
    const unsigned short* __restrict__ Min, int node, int l16,
    float& A0, float& A1, float& A2, float& A3) {
  float a0, a1, a2, a3;
  float b0 = 0.f, b1 = 0.f, b2 = 0.f, b3 = 0.f;
  float c0 = 0.f, c1 = 0.f, c2 = 0.f, c3 = 0.f;
  float d0 = 0.f, d1 = 0.f, d2 = 0.f, d3 = 0.f;
  uint2 v = *(const uint2*)(Min + (size_t)node * 64 + l16 * 4);  // self loop
  a0 = bfu2f(v.x & 0xffffu);
  a1 = bfu2f(v.x >> 16);
  a2 = bfu2f(v.y & 0xffffu);
  a3 = bfu2f(v.y >> 16);
  int start = (node == 0) ? 0 : rs[node - 1];
  int end = rs[node];
  int j = start;
  for (; j + 3 < end; j += 4) {
    int s0 = csr[j], s1 = csr[j + 1], s2 = csr[j + 2], s3 = csr[j + 3];
    uint2 u0 = *(const uint2*)(Min + (size_t)s0 * 64 + l16 * 4);
    uint2 u1 = *(const uint2*)(Min + (size_t)s1 * 64 + l16 * 4);
    uint2 u2 = *(const uint2*)(Min + (size_t)s2 * 64 + l16 * 4);
    uint2 u3 = *(const uint2*)(Min + (size_t)s3 * 64 + l16 * 4);
    ACC4(a0, a1, a2, a3, u0);
    ACC4(b0, b1, b2, b3, u1);
    ACC4(c0, c1, c2, c3, u2);
    ACC4(d0, d1, d2, d3, u3);
  }
  if (j + 1 < end) {
    int s0 = csr[j], s1 = csr[j + 1];
    uint2 u0 = *(const uint2*)(Min + (size_t)s0 * 64 + l16 * 4);
    uint2 u1 = *(const uint2*)(Min + (size_t)s1 * 64 + l16 * 4);
    ACC4(a0, a1, a2, a3, u0);
    ACC4(b0, b1, b2, b3, u1);
    j += 2;
  }
  if (j < end) {
    uint2 u0 = *(const uint2*)(Min + (size_t)csr[j] * 64 + l16 * 4);
    ACC4(a0, a1, a2, a3, u0);
  }
  A0 = (a0 + b0) + (c0 + d0);
  A1 = (a1 + b1) + (c1 + d1);
  A2 = (a2 + b2) + (c2 + d2);
  A3 = (a3 + b3) + (c3 + d3);
}

// ===== fused gather+act+MFMA: Mout = dis * (relu((agg Min)*dis + b) @ W) ====
__global__ __launch_bounds__(256) void k_gmm(
    const int* __restrict__ rs, const int* __restrict__ csr,
    const unsigned short* __restrict__ Min, const float* __restrict__ dis,
    const float* __restrict__ bias, const float* __restrict__ W,
    unsigned short* __restrict__ Mout, int n) {
  __shared__ __align__(16) unsigned short As[64 * 64];
  __shared__ __align__(16) unsigned short Bt[64 * 64];
  const int tid = threadIdx.x;
  const int bm = blockIdx.x * 64;
  // ---- stage Bt[n][k] = W[k][n] bf16, swizzled
  {
    int nn = tid & 63, k0 = (tid >> 6) * 16;
    bf16x8 v0, v1;
#pragma unroll
    for (int i = 0; i < 8; ++i) v0[i] = (short)f2bfu(W[(size_t)(k0 + i) * 64 + nn]);
#pragma unroll
    for (int i = 0; i < 8; ++i) v1[i] = (short)f2bfu(W[(size_t)(k0 + 8 + i) * 64 + nn]);
    int off0 = (nn * 128 + k0 * 2) ^ ((nn & 7) << 4);
    int off1 = (nn * 128 + (k0 + 8) * 2) ^ ((nn & 7) << 4);
    *(bf16x8*)((char*)Bt + off0) = v0;
    *(bf16x8*)((char*)Bt + off1) = v1;
  }
  // ---- gather + act into As
  const int lane = tid & 63;
  const int wv = tid >> 6;
  const int grp = lane >> 4, l16 = lane & 15;
  const float4 bb = *(const float4*)(bias + l16 * 4);
  for (int p = 0; p < 4; ++p) {
    int local = wv * 16 + p * 4 + grp;
    int node = bm + local;
    float A0 = 0.f, A1 = 0.f, A2 = 0.f, A3 = 0.f, dv = 0.f;
    if (node < n) {
      gather_rows(rs, csr, Min, node, l16, A0, A1, A2, A3);
      dv = dis[node];
    }
    ushort4 h;
    h.x = f2bfu(fmaxf(fmaf(A0, dv, bb.x), 0.f));
    h.y = f2bfu(fmaxf(fmaf(A1, dv, bb.y), 0.f));
    h.z = f2bfu(fmaxf(fmaf(A2, dv, bb.z), 0.f));
    h.w = f2bfu(fmaxf(fmaf(A3, dv, bb.w), 0.f));
    int off = (local * 128 + l16 * 8) ^ ((local & 7) << 4);
    *(ushort4*)((char*)As + off) = h;
  }
  __syncthreads();
  // ---- MFMA phase
  const int kb = lane >> 4, fr = lane & 15;
  f32x4 acc[4];
#pragma unroll
  for (int i = 0; i < 4; ++i) acc[i] = f32x4{0.f, 0.f, 0.f, 0.f};
  const int ar = wv * 16 + fr;
#pragma unroll
  for (int kc = 0; kc < 2; ++kc) {
    int aoff = (ar * 128 + kc * 64 + kb * 16) ^ ((ar & 7) << 4);
    bf16x8 a = *(const bf16x8*)((char*)As + aoff);
#pragma unroll
    for (int ni = 0; ni < 4; ++ni) {
      int nr = ni * 16 + fr;
      int boff = (nr * 128 + kc * 64 + kb * 16) ^ ((nr & 7) << 4);
      bf16x8 b = *(const bf16x8*)((char*)Bt + boff);
      acc[ni] = __builtin_amdgcn_mfma_f32_16x16x32_bf16(a, b, acc[ni], 0, 0, 0);
    }
  }
#pragma unroll
  for (int r = 0; r < 4; ++r) {
    int row = bm + wv * 16 + kb * 4 + r;
    if (row < n) {
      float dvo = dis[row];
#pragma unroll
      for (int ni = 0; ni < 4; ++ni)
        Mout[(size_t)row * 64 + ni * 16 + fr] = f2bfu(acc[ni][r] * dvo);
    }
  }
}

// == gather+act: H[d] = relu((M[d] + sum_{s in csr[d]} M[s]) * dis[d] + b) ==
__global__ void k_gather_act(const int* __restrict__ rs, const int* __restrict__ csr,
                             const unsigned short* __restrict__ M,
                             const float* __restrict__ dis, const float* __restrict__ bias,
                             unsigned short* __restrict__ H, int n) {
  int w = (int)((blockIdx.x * (long)blockDim.x + threadIdx.x) >> 6);
  int lane = threadIdx.x & 63;
  int grp = lane >> 4, l16 = lane & 15;
  int node = w * 4 + grp;
  if (node >= n) return;
  float A0, A1, A2, A3;
  gather_rows(rs, csr, M, node, l16, A0, A1, A2, A3);
  float dv = dis[node];
  float4 bb = *(const float4*)(bias + l16 * 4);
  ushort4 o;
  o.x = f2bfu(fmaxf(fmaf(A0, dv, bb.x), 0.f));
  o.y = f2bfu(fmaxf(fmaf(A1, dv, bb.y), 0.f));
  o.z = f2bfu(fmaxf(fmaf(A2, dv, bb.z), 0.f));
  o.w = f2bfu(fmaxf(fmaf(A3, dv, bb.w), 0.f));
  *(ushort4*)(H + (size_t)node * 64 + l16 * 4) = o;
}

// ============ mean pool over sorted batch (H already post-relu) =============
__global__ void k_pool8(const unsigned short* __restrict__ H, const int* __restrict__ batch,
                        float* __restrict__ sums, float* __restrict__ cntf, int n) {
  int w = (int)((blockIdx.x * (long)blockDim.x + threadIdx.x) >> 6);
  int lane = threadIdx.x & 63;
  int r0 = w * 8;
  if (r0 >= n) return;
  int cur = batch[r0];
  float acc = bfu2f(H[(long)r0 * 64 + lane]);
  float c = 1.0f;
  for (int i = 1; i < 8; ++i) {
    int r = r0 + i;
    if (r >= n) break;
    int b = batch[r];
    float v = bfu2f(H[(long)r * 64 + lane]);
    if (b == cur) {
      acc += v;
      c += 1.0f;
    } else {
      unsafeAtomicAdd(&sums[(long)cur * 64 + lane], acc);
      if (lane == 0) unsafeAtomicAdd(&cntf[cur], c);
      cur = b;
      acc = v;
      c = 1.0f;
    }
  }
  unsafeAtomicAdd(&sums[(long)cur * 64 + lane], acc);
  if (lane == 0) unsafeAtomicAdd(&cntf[cur], c);
}

// ================= drug fc: relu((sums/cnt) @ Wd + bd), 64 -> 128 ===========
__global__ void k_drugfc(const float* __restrict__ sums, const float* __restrict__ cnt,
                         const float* __restrict__ W, const float* __restrict__ b,
                         float* __restrict__ out, int B) {
  __shared__ float ps[64];
  int row = blockIdx.x;
  int tid = threadIdx.x;
  float inv = 1.0f / fmaxf(cnt[row], 1.0f);
  if (tid < 64) ps[tid] = sums[(long)row * 64 + tid] * inv;
  __syncthreads();
  float acc = b[tid];
#pragma unroll 8
  for (int k = 0; k < 64; ++k) acc = fmaf(ps[k], W[k * 128 + tid], acc);
  out[(long)row * 128 + tid] = fmaxf(acc, 0.0f);
}

// ============ f32 [M x Kin] -> bf16 [M x ldout], zero-padded cols ===========
__global__ void k_cvt_bf16(const float* __restrict__ X, unsigned short* __restrict__ Y,
                           int Kin, int ldout) {
  int row = blockIdx.x;
  const float* xr = X + (size_t)row * Kin;
  unsigned short* yr = Y + (size_t)row * ldout;
  for (int j = threadIdx.x; j < ldout; j += 256)
    yr[j] = (j < Kin) ? f2bfu(xr[j]) : 0;
}

// ===== bf16 MFMA GEMM, 64x128 tile, BK=32, reg-prefetch double-buffer ======
template <bool SPLIT, typename OT>
__global__ __launch_bounds__(256, 3) void k_gemm2(
    const unsigned short* __restrict__ A, const float* __restrict__ W,
    const float* __restrict__ bias, OT* __restrict__ C,
    int Mrows, int N, int K, int lda, int nsteps, int chunkSteps) {
  __shared__ __align__(16) unsigned short As[2][64 * 32];
  __shared__ __align__(16) unsigned short Bs[2][128 * 32];
  const int tid = threadIdx.x;
  const int lane = tid & 63;
  const int wid = tid >> 6;
  const int bm = blockIdx.x * 64;
  const int bn = blockIdx.y * 128;
  const int kb = lane >> 4, fr = lane & 15;
  const int ss0 = blockIdx.z * chunkSteps;
  const int ss1 = min(nsteps, ss0 + chunkSteps);

  f32x4 acc[8];
#pragma unroll
  for (int j = 0; j < 8; ++j) acc[j] = f32x4{0.f, 0.f, 0.f, 0.f};

  const int ar = wid * 16 + fr;
  const int aOff = (ar * 64 + kb * 16) ^ ((ar & 7) << 4);
  int bOff[8];
#pragma unroll
  for (int ni = 0; ni < 8; ++ni) {
    int nr = ni * 16 + fr;
    bOff[ni] = (nr * 64 + kb * 16) ^ ((nr & 7) << 4);
  }
  const int arow = tid >> 2, ac = tid & 3;
  const int aW = (arow * 64 + ac * 16) ^ ((arow & 7) << 4);
  const int bn_ = tid & 127, bk0 = (tid >> 7) * 2;
  int bW[2];
#pragma unroll
  for (int p = 0; p < 2; ++p) {
    int kbb = bk0 + p;
    bW[p] = (bn_ * 64 + kbb * 16) ^ ((bn_ & 7) << 4);
  }

  bf16x8 pa;
  float pb[2][8];
  const unsigned short* aptr = A + (size_t)(bm + arow) * lda + ac * 8;

#define LOAD_STEP(S)                                              \
  {                                                               \
    int k0 = (S) * 32;                                            \
    pa = *(const bf16x8*)(aptr + k0);                             \
    _Pragma("unroll") for (int p = 0; p < 2; ++p) {               \
      _Pragma("unroll") for (int i = 0; i < 8; ++i) {             \
        int gk = k0 + (bk0 + p) * 8 + i;                          \
        pb[p][i] = (gk < K) ? W[(size_t)gk * N + bn + bn_] : 0.f; \
      }                                                           \
    }                                                             \
  }
#define STORE_STEP(BUF)                                           \
  {                                                               \
    *(bf16x8*)((char*)As[BUF] + aW) = pa;                         \
    _Pragma("unroll") for (int p = 0; p < 2; ++p) {               \
      bf16x8 v;                                                   \
      _Pragma("unroll") for (int i = 0; i < 8; ++i)               \
          v[i] = (short)f2bfu(pb[p][i]);                          \
      *(bf16x8*)((char*)Bs[BUF] + bW[p]) = v;                     \
    }                                                             \
  }

  LOAD_STEP(ss0);
  STORE_STEP(0);
  __syncthreads();
  int cur = 0;
  for (int s = ss0; s < ss1; ++s) {
    bool more = (s + 1 < ss1);
    if (more) LOAD_STEP(s + 1);
    bf16x8 a0 = *(const bf16x8*)((char*)As[cur] + aOff);
#pragma unroll
    for (int ni = 0; ni < 8; ++ni) {
      bf16x8 b = *(const bf16x8*)((char*)Bs[cur] + bOff[ni]);
      acc[ni] = __builtin_amdgcn_mfma_f32_16x16x32_bf16(a0, b, acc[ni], 0, 0, 0);
    }
    if (more) {
      STORE_STEP(cur ^ 1);
      __syncthreads();
      cur ^= 1;
    }
  }
  if constexpr (SPLIT) {
    float* Cz = (float*)C + (size_t)blockIdx.z * Mrows * N;
#pragma unroll
    for (int ni = 0; ni < 8; ++ni)
#pragma unroll
      for (int r = 0; r < 4; ++r) {
        int row = bm + wid * 16 + kb * 4 + r;
        int col = bn + ni * 16 + fr;
        Cz[(size_t)row * N + col] = acc[ni][r];
      }
  } else {
    float bv[8];
#pragma unroll
    for (int ni = 0; ni < 8; ++ni) bv[ni] = bias[bn + ni * 16 + fr];
#pragma unroll
    for (int ni = 0; ni < 8; ++ni)
#pragma unroll
      for (int r = 0; r < 4; ++r) {
        int row = bm + wid * 16 + kb * 4 + r;
        int col = bn + ni * 16 + fr;
        float x = fmaxf(acc[ni][r] + bv[ni], 0.f);
        if constexpr (__hip_internal::is_same<OT, float>::value) {
          C[(size_t)row * N + col] = x;
        } else {
          C[(size_t)row * N + col] = f2bfu(x);
        }
      }
  }
#undef LOAD_STEP
#undef STORE_STEP
}

// ---- concat + LayerNorm; prot = relu(sum of 4 K-split partials + bp) -------
__global__ void k_concat_ln(const float* __restrict__ drug, const float* __restrict__ protP,
                            const float* __restrict__ bp, const float* __restrict__ fpp,
                            unsigned short* __restrict__ comb, int B) {
  __shared__ float buf[CONCAT_F];
  __shared__ float rs[4], rs2[4];
  int row = blockIdx.x;
  int tid = threadIdx.x;
  const size_t MN = (size_t)B * 128;
  float s = 0.0f, s2 = 0.0f;
  for (int j = tid; j < CONCAT_F; j += 256) {
    float v;
    if (j < 128) {
      v = drug[(long)row * 128 + j];
    } else if (j < 256) {
      int c = j - 128;
      size_t o = (size_t)row * 128 + c;
      float acc = protP[o] + protP[MN + o] + protP[2 * MN + o] + protP[3 * MN + o];
      v = fmaxf(acc + bp[c], 0.0f);
    } else {
      v = fpp[(long)row * 881 + (j - 256)];
    }
    buf[j] = v;
    s += v;
    s2 += v * v;
  }
  for (int o = 32; o; o >>= 1) {
    s += __shfl_down(s, o, 64);
    s2 += __shfl_down(s2, o, 64);
  }
  int lane = tid & 63, wid = tid >> 6;
  if (lane == 0) { rs[wid] = s; rs2[wid] = s2; }
  __syncthreads();
  if (tid == 0) {
    float ts = rs[0] + rs[1] + rs[2] + rs[3];
    float ts2 = rs2[0] + rs2[1] + rs2[2] + rs2[3];
    float mu = ts / (float)CONCAT_F;
    float var = ts2 / (float)CONCAT_F - mu * mu;
    rs[0] = mu;
    rs2[0] = rsqrtf(fmaxf(var, 0.0f) + 1e-5f);
  }
  __syncthreads();
  float mu = rs[0], inv = rs2[0];
  for (int j = tid; j < CONCAT_P; j += 256) {
    unsigned short o = (j < CONCAT_F) ? f2bfu((buf[j] - mu) * inv) : 0;
    comb[(long)row * CONCAT_P + j] = o;
  }
}

// ---------------- fc3: X @ w + b, 256 -> 1 ----------------------------------
__global__ void k_fc3(const float* __restrict__ X, const float* __restrict__ W,
                      const float* __restrict__ bias, float* __restrict__ out, int B) {
  int w = (int)((blockIdx.x * (long)blockDim.x + threadIdx.x) >> 6);
  int lane = threadIdx.x & 63;
  if (w >= B) return;
  float s = 0.0f;
#pragma unroll
  for (int j = 0; j < 4; ++j) s = fmaf(X[(long)w * 256 + lane + j * 64], W[lane + j * 64], s);
  for (int o = 32; o; o >>= 1) s += __shfl_down(s, o, 64);
  if (lane == 0) out[w] = s + bias[0];
}

// ---------------------------------------------------------------------------
extern "C" void kernel_launch(void* const* d_in, const int* in_sizes, int n_in,
                              void* d_out, int out_size, void* d_ws, size_t ws_size,
                              hipStream_t stream) {
  const float* drug_x = (const float*)d_in[0];
  const int* ei = (const int*)d_in[1];
  const int* batch = (const int*)d_in[2];
  const float* protein_x = (const float*)d_in[3];
  const float* fpp = (const float*)d_in[4];
  const float* W1 = (const float*)d_in[5];
  const float* b1 = (const float*)d_in[6];
  const float* W2 = (const float*)d_in[7];
  const float* b2 = (const float*)d_in[8];
  const float* W3 = (const float*)d_in[9];
  const float* b3 = (const float*)d_in[10];
  const float* Wd = (const float*)d_in[11];
  const float* bd = (const float*)d_in[12];
  const float* Wp = (const float*)d_in[13];
  const float* bp = (const float*)d_in[14];
  const float* Wf1 = (const float*)d_in[15];
  const float* bf1 = (const float*)d_in[16];
  const float* Wf2 = (const float*)d_in[17];
  const float* bf2 = (const float*)d_in[18];
  const float* Wf3 = (const float*)d_in[19];
  const float* bf3 = (const float*)d_in[20];
  float* out = (float*)d_out;

  const int N = in_sizes[0] / 30;
  const int E = in_sizes[1] / 2;
  const int B = in_sizes[4] / 881;

  // ---- GCN-phase workspace (4-byte words) ----
  int* rs = (int*)d_ws;
  float* dis = (float*)d_ws + ((size_t)N + 1);
  int* csr = (int*)d_ws + (2 * (size_t)N + 1);
  size_t oM = 2 * (size_t)N + 2 + (size_t)E;
  unsigned short* M = (unsigned short*)((float*)d_ws + oM);
  unsigned short* H = M + (size_t)N * 64;
  float* sums = (float*)d_ws + (oM + 64 * (size_t)N);
  float* cntf = sums + (size_t)B * 64;
  int* part = (int*)(cntf + B);
  int* bkt = part + 1024;                                   // 4096 ints
  unsigned short* protbh = (unsigned short*)(bkt + 4096);   // B*PROT_P bf16
  int2* pairs = (int2*)H;                                   // E*8B, dead before k_gmm writes H
  // ---- dense-tail aliases at offset 0 (GCN buffers dead by then) ----
  float* tail = (float*)d_ws;
  float* drug = tail;                                        // B*128 f32
  float* protP = drug + (size_t)B * 128;                     // 4*B*128 f32 partials
  unsigned short* combh = (unsigned short*)(protP + 4 * (size_t)B * 128);  // B*1152 bf16
  unsigned short* act1h = combh + (size_t)B * CONCAT_P;      // B*512 bf16
  float* act2 = (float*)(act1h + (size_t)B * 512);           // B*256 f32

  const int* srcIdx = ei;
  const int* dstIdx = ei + E;

  // ---- protein f32 -> bf16 ----
  k_cvt_bf16<<<B, 256, 0, stream>>>(protein_x, protbh, PROT_K, PROT_P);

  // ---- bucketed CSR build + degree ----
  const int NBUK = (N + 1023) >> 10;  // 512
  hipMemsetAsync(rs, 0, ((size_t)N + 1) * sizeof(int), stream);
  hipMemsetAsync(bkt, 0, (size_t)NBUK * 8 * sizeof(int), stream);
  int EB = (E + 255) / 256;
  k_bcount<<<EB, 256, 0, stream>>>(dstIdx, bkt, E);
  k_bscan<<<1, 1024, 0, stream>>>(bkt, NBUK * 8);
  k_bscatter<<<EB, 256, 0, stream>>>(srcIdx, dstIdx, bkt, pairs, E);
  k_pcount<<<NBUK, 256, 0, stream>>>(pairs, bkt, rs);
  k_disk<<<(N + 255) / 256, 256, 0, stream>>>(rs, dis, N);
  int NB = (N + 1023) / 1024;
  k_scan_p1<<<NB, 256, 0, stream>>>(rs, part, N);
  k_scan_p2<<<1, 1024, 0, stream>>>(part, NB);
  k_scan_p3<<<NB, 256, 0, stream>>>(rs, part, N);
  k_scatter2<<<NBUK, 256, 0, stream>>>(pairs, bkt, rs, csr);

  // ---- GCN layers ----
  int mmBlocks = (N + 63) / 64;
  int gWaves = (N + 3) / 4;
  int gBlocks = (gWaves + 3) / 4;
  k_mm<30, false><<<mmBlocks, 256, 0, stream>>>(drug_x, W1, nullptr, dis, M, N);
  k_gmm<<<mmBlocks, 256, 0, stream>>>(rs, csr, M, dis, b1, W2, H, N);  // H = M2
  k_gmm<<<mmBlocks, 256, 0, stream>>>(rs, csr, H, dis, b2, W3, M, N);  // M = M3
  k_gather_act<<<gBlocks, 256, 0, stream>>>(rs, csr, M, dis, b3, H, N);

  // ---- mean pool ----
  hipMemsetAsync(sums, 0, ((size_t)B * 64 + B) * sizeof(float), stream);
  int poolWaves = (N + 7) / 8;
  k_pool8<<<(poolWaves + 3) / 4, 256, 0, stream>>>(H, batch, sums, cntf, N);

  // ---- dense tail ----
  k_drugfc<<<B, 128, 0, stream>>>(sums, cntf, Wd, bd, drug, B);
  k_gemm2<true, float><<<dim3(B / 64, 1, 4), 256, 0, stream>>>(
      protbh, Wp, nullptr, protP, B, 128, PROT_K, PROT_P, 31, 8);
  k_concat_ln<<<B, 256, 0, stream>>>(drug, protP, bp, fpp, combh, B);
  k_gemm2<false, unsigned short><<<dim3(B / 64, 4, 1), 256, 0, stream>>>(
      combh, Wf1, bf1, act1h, B, 512, CONCAT_F, CONCAT_P, 36, 36);
  k_gemm2<false, float><<<dim3(B / 64, 2, 1), 256, 0, stream>>>(
      act1h, Wf2, bf2, act2, B, 256, 512, 512, 16, 16);
  k_fc3<<<(B + 3) / 4, 256, 0, stream>>>(act2, Wf3, bf3, out, B);
}

// Round 11
// 884.733 us; speedup vs baseline: 1.1896x; 1.1896x over previous
//
#include <hip/hip_runtime.h>
#include <hip/hip_bf16.h>

#define CONCAT_F 1137
#define CONCAT_P 1152  // padded to multiple of 32 for bf16 MFMA GEMM
#define PROT_K 979
#define PROT_P 992     // 979 padded to 31*32

typedef __attribute__((ext_vector_type(8))) short bf16x8;
typedef __attribute__((ext_vector_type(4))) float f32x4;

static __device__ __forceinline__ float bfu2f(unsigned short u) {
  return __uint_as_float(((unsigned)u) << 16);
}
static __device__ __forceinline__ unsigned short f2bfu(float v) {
  __hip_bfloat16 t = __float2bfloat16(v);
  unsigned short u;
  __builtin_memcpy(&u, &t, 2);
  return u;
}

// accumulate a bf16x4 row chunk (uint2) into 4 floats
#define ACC4(A0, A1, A2, A3, U)        \
  {                                    \
    A0 += bfu2f((U).x & 0xffffu);      \
    A1 += bfu2f((U).x >> 16);          \
    A2 += bfu2f((U).y & 0xffffu);      \
    A3 += bfu2f((U).y >> 16);          \
  }

// ================= CSR build =================
__global__ void k_count(const int* __restrict__ dst, int* __restrict__ rs, int E) {
  int e = blockIdx.x * blockDim.x + threadIdx.x;
  if (e < E) atomicAdd(&rs[dst[e]], 1);
}

// block partial sums AND dis = rsqrt(1+cnt) (fused former k_disk)
__global__ void k_scan_p1(const int* __restrict__ cnt, int* __restrict__ part,
                          float* __restrict__ dis, int n) {
  __shared__ int red[256];
  int tid = threadIdx.x;
  long base = (long)blockIdx.x * 1024 + tid * 4;
  int s = 0;
#pragma unroll
  for (int i = 0; i < 4; ++i) {
    long j = base + i;
    if (j < n) {
      int c = cnt[j];
      s += c;
      dis[j] = rsqrtf(1.0f + (float)c);
    }
  }
  red[tid] = s;
  __syncthreads();
  for (int off = 128; off; off >>= 1) {
    if (tid < off) red[tid] += red[tid + off];
    __syncthreads();
  }
  if (tid == 0) part[blockIdx.x] = red[0];
}

__global__ void k_scan_p2(int* __restrict__ part, int nb) {
  __shared__ int a[1024], b_[1024];
  int t = threadIdx.x;
  a[t] = (t < nb) ? part[t] : 0;
  __syncthreads();
  int* s = a;
  int* d = b_;
  for (int off = 1; off < 1024; off <<= 1) {
    d[t] = s[t] + ((t >= off) ? s[t - off] : 0);
    __syncthreads();
    int* tmp = s;
    s = d;
    d = tmp;
  }
  if (t < nb) part[t] = (t == 0) ? 0 : s[t - 1];  // exclusive
}

__global__ void k_scan_p3(int* __restrict__ rs, const int* __restrict__ part, int n) {
  __shared__ int a[256], b_[256];
  int tid = threadIdx.x;
  long base = (long)blockIdx.x * 1024 + tid * 4;
  int v[4];
#pragma unroll
  for (int i = 0; i < 4; ++i) {
    long j = base + i;
    v[i] = (j < n) ? rs[j] : 0;
  }
  a[tid] = v[0] + v[1] + v[2] + v[3];
  __syncthreads();
  int* s = a;
  int* d = b_;
  for (int off = 1; off < 256; off <<= 1) {
    d[tid] = s[tid] + ((tid >= off) ? s[tid - off] : 0);
    __syncthreads();
    int* t2 = s;
    s = d;
    d = t2;
  }
  int run = part[blockIdx.x] + ((tid == 0) ? 0 : s[tid - 1]);
#pragma unroll
  for (int i = 0; i < 4; ++i) {
    long j = base + i;
    if (j < n) {
      rs[j] = run;
      run += v[i];
    }
  }
}

// ==== fat kernel: co-scheduled {csr-scatter | layer-1 matmul | prot cvt} ====
// blocks [0, EB): scatter; [EB, EB+mmB): mm1 (K=30); [EB+mmB, ...): cvt.
// All three are mutually independent; scatter is memory-system-bound at ~11%
// HBM / 0.3% VALU, so mm1+cvt execute in its shadow.
__global__ __launch_bounds__(256) void k_fat(
    const int* __restrict__ src, const int* __restrict__ dst,
    int* __restrict__ rs, int* __restrict__ csr, int E, int EB,
    const float* __restrict__ X, const float* __restrict__ W1,
    const float* __restrict__ dis, unsigned short* __restrict__ M, int n, int mmB,
    const float* __restrict__ PX, unsigned short* __restrict__ PY) {
  __shared__ __align__(16) float hT[30][68];
  __shared__ __align__(16) float Ws[30 * 64];
  __shared__ float disS[64];
  int bx = blockIdx.x;
  int tid = threadIdx.x;
  if (bx < EB) {
    // ---- csr scatter (rowStart-shift: rs[d] ends as exclusive_end(d))
    int e = bx * 256 + tid;
    if (e < E) {
      int pos = atomicAdd(&rs[dst[e]], 1);
      __builtin_nontemporal_store(src[e], &csr[pos]);
    }
    return;
  }
  bx -= EB;
  if (bx < mmB) {
    // ---- layer-1 matmul: M = dis*(X@W1), f32 in, bf16 out, K=30
    const int K = 30;
    int rb = bx * 64;
    for (int j = tid; j < K * 16; j += 256) ((float4*)Ws)[j] = ((const float4*)W1)[j];
    if (tid < 64) disS[tid] = (rb + tid < n) ? dis[rb + tid] : 0.0f;
    __syncthreads();
    for (int idx = tid; idx < 64 * K; idx += 256) {
      int r = idx / K, k = idx - r * K;
      hT[k][r] = (rb + r < n) ? X[(long)(rb + r) * K + k] : 0.0f;
    }
    __syncthreads();
    int rt = (tid & 15) * 4;
    int ct = (tid >> 4) * 4;
    float acc[4][4] = {};
#pragma unroll 5
    for (int k = 0; k < K; ++k) {
      float4 xr = *(const float4*)&hT[k][rt];
      float4 wr = *(const float4*)&Ws[k * 64 + ct];
      float xa[4] = {xr.x, xr.y, xr.z, xr.w};
      float wa[4] = {wr.x, wr.y, wr.z, wr.w};
#pragma unroll
      for (int i = 0; i < 4; ++i)
#pragma unroll
        for (int j = 0; j < 4; ++j) acc[i][j] = fmaf(xa[i], wa[j], acc[i][j]);
    }
#pragma unroll
    for (int i = 0; i < 4; ++i) {
      int row = rb + rt + i;
      if (row >= n) break;
      float dv = disS[rt + i];
      ushort4 pk;
      pk.x = f2bfu(acc[i][0] * dv);
      pk.y = f2bfu(acc[i][1] * dv);
      pk.z = f2bfu(acc[i][2] * dv);
      pk.w = f2bfu(acc[i][3] * dv);
      *(ushort4*)&M[(long)row * 64 + ct] = pk;
    }
    return;
  }
  bx -= mmB;
  // ---- protein f32 -> bf16, zero-padded to PROT_P
  {
    const float* xr = PX + (size_t)bx * PROT_K;
    unsigned short* yr = PY + (size_t)bx * PROT_P;
    for (int j = tid; j < PROT_P; j += 256)
      yr[j] = (j < PROT_K) ? f2bfu(xr[j]) : 0;
  }
}

// ---- 4-edge-unrolled row aggregation body (16 lanes x uint2 per row) -------
static __device__ __forceinline__ void gather_rows(
    const int* __restrict__ rs, const int* __restrict__ csr,
    const unsigned short* __restrict__ Min, int node, int l16,
    float& A0, float& A1, float& A2, float& A3) {
  float a0, a1, a2, a3;
  float b0 = 0.f, b1 = 0.f, b2 = 0.f, b3 = 0.f;
  float c0 = 0.f, c1 = 0.f, c2 = 0.f, c3 = 0.f;
  float d0 = 0.f, d1 = 0.f, d2 = 0.f, d3 = 0.f;
  uint2 v = *(const uint2*)(Min + (size_t)node * 64 + l16 * 4);  // self loop
  a0 = bfu2f(v.x & 0xffffu);
  a1 = bfu2f(v.x >> 16);
  a2 = bfu2f(v.y & 0xffffu);
  a3 = bfu2f(v.y >> 16);
  int start = (node == 0) ? 0 : rs[node - 1];
  int end = rs[node];
  int j = start;
  for (; j + 3 < end; j += 4) {
    int s0 = csr[j], s1 = csr[j + 1], s2 = csr[j + 2], s3 = csr[j + 3];
    uint2 u0 = *(const uint2*)(Min + (size_t)s0 * 64 + l16 * 4);
    uint2 u1 = *(const uint2*)(Min + (size_t)s1 * 64 + l16 * 4);
    uint2 u2 = *(const uint2*)(Min + (size_t)s2 * 64 + l16 * 4);
    uint2 u3 = *(const uint2*)(Min + (size_t)s3 * 64 + l16 * 4);
    ACC4(a0, a1, a2, a3, u0);
    ACC4(b0, b1, b2, b3, u1);
    ACC4(c0, c1, c2, c3, u2);
    ACC4(d0, d1, d2, d3, u3);
  }
  if (j + 1 < end) {
    int s0 = csr[j], s1 = csr[j + 1];
    uint2 u0 = *(const uint2*)(Min + (size_t)s0 * 64 + l16 * 4);
    uint2 u1 = *(const uint2*)(Min + (size_t)s1 * 64 + l16 * 4);
    ACC4(a0, a1, a2, a3, u0);
    ACC4(b0, b1, b2, b3, u1);
    j += 2;
  }
  if (j < end) {
    uint2 u0 = *(const uint2*)(Min + (size_t)csr[j] * 64 + l16 * 4);
    ACC4(a0, a1, a2, a3, u0);
  }
  A0 = (a0 + b0) + (c0 + d0);
  A1 = (a1 + b1) + (c1 + d1);
  A2 = (a2 + b2) + (c2 + d2);
  A3 = (a3 + b3) + (c3 + d3);
}

// ===== fused gather+act+MFMA: Mout = dis * (relu((agg Min)*dis + b) @ W) ====
__global__ __launch_bounds__(256) void k_gmm(
    const int* __restrict__ rs, const int* __restrict__ csr,
    const unsigned short* __restrict__ Min, const float* __restrict__ dis,
    const float* __restrict__ bias, const float* __restrict__ W,
    unsigned short* __restrict__ Mout, int n) {
  __shared__ __align__(16) unsigned short As[64 * 64];
  __shared__ __align__(16) unsigned short Bt[64 * 64];
  const int tid = threadIdx.x;
  const int bm = blockIdx.x * 64;
  // ---- stage Bt[n][k] = W[k][n] bf16, swizzled
  {
    int nn = tid & 63, k0 = (tid >> 6) * 16;
    bf16x8 v0, v1;
#pragma unroll
    for (int i = 0; i < 8; ++i) v0[i] = (short)f2bfu(W[(size_t)(k0 + i) * 64 + nn]);
#pragma unroll
    for (int i = 0; i < 8; ++i) v1[i] = (short)f2bfu(W[(size_t)(k0 + 8 + i) * 64 + nn]);
    int off0 = (nn * 128 + k0 * 2) ^ ((nn & 7) << 4);
    int off1 = (nn * 128 + (k0 + 8) * 2) ^ ((nn & 7) << 4);
    *(bf16x8*)((char*)Bt + off0) = v0;
    *(bf16x8*)((char*)Bt + off1) = v1;
  }
  // ---- gather + act into As
  const int lane = tid & 63;
  const int wv = tid >> 6;
  const int grp = lane >> 4, l16 = lane & 15;
  const float4 bb = *(const float4*)(bias + l16 * 4);
  for (int p = 0; p < 4; ++p) {
    int local = wv * 16 + p * 4 + grp;
    int node = bm + local;
    float A0 = 0.f, A1 = 0.f, A2 = 0.f, A3 = 0.f, dv = 0.f;
    if (node < n) {
      gather_rows(rs, csr, Min, node, l16, A0, A1, A2, A3);
      dv = dis[node];
    }
    ushort4 h;
    h.x = f2bfu(fmaxf(fmaf(A0, dv, bb.x), 0.f));
    h.y = f2bfu(fmaxf(fmaf(A1, dv, bb.y), 0.f));
    h.z = f2bfu(fmaxf(fmaf(A2, dv, bb.z), 0.f));
    h.w = f2bfu(fmaxf(fmaf(A3, dv, bb.w), 0.f));
    int off = (local * 128 + l16 * 8) ^ ((local & 7) << 4);
    *(ushort4*)((char*)As + off) = h;
  }
  __syncthreads();
  // ---- MFMA phase
  const int kb = lane >> 4, fr = lane & 15;
  f32x4 acc[4];
#pragma unroll
  for (int i = 0; i < 4; ++i) acc[i] = f32x4{0.f, 0.f, 0.f, 0.f};
  const int ar = wv * 16 + fr;
#pragma unroll
  for (int kc = 0; kc < 2; ++kc) {
    int aoff = (ar * 128 + kc * 64 + kb * 16) ^ ((ar & 7) << 4);
    bf16x8 a = *(const bf16x8*)((char*)As + aoff);
#pragma unroll
    for (int ni = 0; ni < 4; ++ni) {
      int nr = ni * 16 + fr;
      int boff = (nr * 128 + kc * 64 + kb * 16) ^ ((nr & 7) << 4);
      bf16x8 b = *(const bf16x8*)((char*)Bt + boff);
      acc[ni] = __builtin_amdgcn_mfma_f32_16x16x32_bf16(a, b, acc[ni], 0, 0, 0);
    }
  }
#pragma unroll
  for (int r = 0; r < 4; ++r) {
    int row = bm + wv * 16 + kb * 4 + r;
    if (row < n) {
      float dvo = dis[row];
#pragma unroll
      for (int ni = 0; ni < 4; ++ni)
        Mout[(size_t)row * 64 + ni * 16 + fr] = f2bfu(acc[ni][r] * dvo);
    }
  }
}

// == gather+act: H[d] = relu((M[d] + sum_{s in csr[d]} M[s]) * dis[d] + b) ==
__global__ void k_gather_act(const int* __restrict__ rs, const int* __restrict__ csr,
                             const unsigned short* __restrict__ M,
                             const float* __restrict__ dis, const float* __restrict__ bias,
                             unsigned short* __restrict__ H, int n) {
  int w = (int)((blockIdx.x * (long)blockDim.x + threadIdx.x) >> 6);
  int lane = threadIdx.x & 63;
  int grp = lane >> 4, l16 = lane & 15;
  int node = w * 4 + grp;
  if (node >= n) return;
  float A0, A1, A2, A3;
  gather_rows(rs, csr, M, node, l16, A0, A1, A2, A3);
  float dv = dis[node];
  float4 bb = *(const float4*)(bias + l16 * 4);
  ushort4 o;
  o.x = f2bfu(fmaxf(fmaf(A0, dv, bb.x), 0.f));
  o.y = f2bfu(fmaxf(fmaf(A1, dv, bb.y), 0.f));
  o.z = f2bfu(fmaxf(fmaf(A2, dv, bb.z), 0.f));
  o.w = f2bfu(fmaxf(fmaf(A3, dv, bb.w), 0.f));
  *(ushort4*)(H + (size_t)node * 64 + l16 * 4) = o;
}

// ============ mean pool over sorted batch (H already post-relu) =============
__global__ void k_pool8(const unsigned short* __restrict__ H, const int* __restrict__ batch,
                        float* __restrict__ sums, float* __restrict__ cntf, int n) {
  int w = (int)((blockIdx.x * (long)blockDim.x + threadIdx.x) >> 6);
  int lane = threadIdx.x & 63;
  int r0 = w * 8;
  if (r0 >= n) return;
  int cur = batch[r0];
  float acc = bfu2f(H[(long)r0 * 64 + lane]);
  float c = 1.0f;
  for (int i = 1; i < 8; ++i) {
    int r = r0 + i;
    if (r >= n) break;
    int b = batch[r];
    float v = bfu2f(H[(long)r * 64 + lane]);
    if (b == cur) {
      acc += v;
      c += 1.0f;
    } else {
      unsafeAtomicAdd(&sums[(long)cur * 64 + lane], acc);
      if (lane == 0) unsafeAtomicAdd(&cntf[cur], c);
      cur = b;
      acc = v;
      c = 1.0f;
    }
  }
  unsafeAtomicAdd(&sums[(long)cur * 64 + lane], acc);
  if (lane == 0) unsafeAtomicAdd(&cntf[cur], c);
}

// ================= drug fc: relu((sums/cnt) @ Wd + bd), 64 -> 128 ===========
__global__ void k_drugfc(const float* __restrict__ sums, const float* __restrict__ cnt,
                         const float* __restrict__ W, const float* __restrict__ b,
                         float* __restrict__ out, int B) {
  __shared__ float ps[64];
  int row = blockIdx.x;
  int tid = threadIdx.x;
  float inv = 1.0f / fmaxf(cnt[row], 1.0f);
  if (tid < 64) ps[tid] = sums[(long)row * 64 + tid] * inv;
  __syncthreads();
  float acc = b[tid];
#pragma unroll 8
  for (int k = 0; k < 64; ++k) acc = fmaf(ps[k], W[k * 128 + tid], acc);
  out[(long)row * 128 + tid] = fmaxf(acc, 0.0f);
}

// ===== bf16 MFMA GEMM, 64x128 tile, BK=32, reg-prefetch double-buffer ======
template <bool SPLIT, typename OT>
__global__ __launch_bounds__(256, 3) void k_gemm2(
    const unsigned short* __restrict__ A, const float* __restrict__ W,
    const float* __restrict__ bias, OT* __restrict__ C,
    int Mrows, int N, int K, int lda, int nsteps, int chunkSteps) {
  __shared__ __align__(16) unsigned short As[2][64 * 32];
  __shared__ __align__(16) unsigned short Bs[2][128 * 32];
  const int tid = threadIdx.x;
  const int lane = tid & 63;
  const int wid = tid >> 6;
  const int bm = blockIdx.x * 64;
  const int bn = blockIdx.y * 128;
  const int kb = lane >> 4, fr = lane & 15;
  const int ss0 = blockIdx.z * chunkSteps;
  const int ss1 = min(nsteps, ss0 + chunkSteps);

  f32x4 acc[8];
#pragma unroll
  for (int j = 0; j < 8; ++j) acc[j] = f32x4{0.f, 0.f, 0.f, 0.f};

  const int ar = wid * 16 + fr;
  const int aOff = (ar * 64 + kb * 16) ^ ((ar & 7) << 4);
  int bOff[8];
#pragma unroll
  for (int ni = 0; ni < 8; ++ni) {
    int nr = ni * 16 + fr;
    bOff[ni] = (nr * 64 + kb * 16) ^ ((nr & 7) << 4);
  }
  const int arow = tid >> 2, ac = tid & 3;
  const int aW = (arow * 64 + ac * 16) ^ ((arow & 7) << 4);
  const int bn_ = tid & 127, bk0 = (tid >> 7) * 2;
  int bW[2];
#pragma unroll
  for (int p = 0; p < 2; ++p) {
    int kbb = bk0 + p;
    bW[p] = (bn_ * 64 + kbb * 16) ^ ((bn_ & 7) << 4);
  }

  bf16x8 pa;
  float pb[2][8];
  const unsigned short* aptr = A + (size_t)(bm + arow) * lda + ac * 8;

#define LOAD_STEP(S)                                              \
  {                                                               \
    int k0 = (S) * 32;                                            \
    pa = *(const bf16x8*)(aptr + k0);                             \
    _Pragma("unroll") for (int p = 0; p < 2; ++p) {               \
      _Pragma("unroll") for (int i = 0; i < 8; ++i) {             \
        int gk = k0 + (bk0 + p) * 8 + i;                          \
        pb[p][i] = (gk < K) ? W[(size_t)gk * N + bn + bn_] : 0.f; \
      }                                                           \
    }                                                             \
  }
#define STORE_STEP(BUF)                                           \
  {                                                               \
    *(bf16x8*)((char*)As[BUF] + aW) = pa;                         \
    _Pragma("unroll") for (int p = 0; p < 2; ++p) {               \
      bf16x8 v;                                                   \
      _Pragma("unroll") for (int i = 0; i < 8; ++i)               \
          v[i] = (short)f2bfu(pb[p][i]);                          \
      *(bf16x8*)((char*)Bs[BUF] + bW[p]) = v;                     \
    }                                                             \
  }

  LOAD_STEP(ss0);
  STORE_STEP(0);
  __syncthreads();
  int cur = 0;
  for (int s = ss0; s < ss1; ++s) {
    bool more = (s + 1 < ss1);
    if (more) LOAD_STEP(s + 1);
    bf16x8 a0 = *(const bf16x8*)((char*)As[cur] + aOff);
#pragma unroll
    for (int ni = 0; ni < 8; ++ni) {
      bf16x8 b = *(const bf16x8*)((char*)Bs[cur] + bOff[ni]);
      acc[ni] = __builtin_amdgcn_mfma_f32_16x16x32_bf16(a0, b, acc[ni], 0, 0, 0);
    }
    if (more) {
      STORE_STEP(cur ^ 1);
      __syncthreads();
      cur ^= 1;
    }
  }
  if constexpr (SPLIT) {
    float* Cz = (float*)C + (size_t)blockIdx.z * Mrows * N;
#pragma unroll
    for (int ni = 0; ni < 8; ++ni)
#pragma unroll
      for (int r = 0; r < 4; ++r) {
        int row = bm + wid * 16 + kb * 4 + r;
        int col = bn + ni * 16 + fr;
        Cz[(size_t)row * N + col] = acc[ni][r];
      }
  } else {
    float bv[8];
#pragma unroll
    for (int ni = 0; ni < 8; ++ni) bv[ni] = bias[bn + ni * 16 + fr];
#pragma unroll
    for (int ni = 0; ni < 8; ++ni)
#pragma unroll
      for (int r = 0; r < 4; ++r) {
        int row = bm + wid * 16 + kb * 4 + r;
        int col = bn + ni * 16 + fr;
        float x = fmaxf(acc[ni][r] + bv[ni], 0.f);
        if constexpr (__hip_internal::is_same<OT, float>::value) {
          C[(size_t)row * N + col] = x;
        } else {
          C[(size_t)row * N + col] = f2bfu(x);
        }
      }
  }
#undef LOAD_STEP
#undef STORE_STEP
}

// ---- concat + LayerNorm; prot = relu(sum of 4 K-split partials + bp) -------
__global__ void k_concat_ln(const float* __restrict__ drug, const float* __restrict__ protP,
                            const float* __restrict__ bp, const float* __restrict__ fpp,
                            unsigned short* __restrict__ comb, int B) {
  __shared__ float buf[CONCAT_F];
  __shared__ float rs[4], rs2[4];
  int row = blockIdx.x;
  int tid = threadIdx.x;
  const size_t MN = (size_t)B * 128;
  float s = 0.0f, s2 = 0.0f;
  for (int j = tid; j < CONCAT_F; j += 256) {
    float v;
    if (j < 128) {
      v = drug[(long)row * 128 + j];
    } else if (j < 256) {
      int c = j - 128;
      size_t o = (size_t)row * 128 + c;
      float acc = protP[o] + protP[MN + o] + protP[2 * MN + o] + protP[3 * MN + o];
      v = fmaxf(acc + bp[c], 0.0f);
    } else {
      v = fpp[(long)row * 881 + (j - 256)];
    }
    buf[j] = v;
    s += v;
    s2 += v * v;
  }
  for (int o = 32; o; o >>= 1) {
    s += __shfl_down(s, o, 64);
    s2 += __shfl_down(s2, o, 64);
  }
  int lane = tid & 63, wid = tid >> 6;
  if (lane == 0) { rs[wid] = s; rs2[wid] = s2; }
  __syncthreads();
  if (tid == 0) {
    float ts = rs[0] + rs[1] + rs[2] + rs[3];
    float ts2 = rs2[0] + rs2[1] + rs2[2] + rs2[3];
    float mu = ts / (float)CONCAT_F;
    float var = ts2 / (float)CONCAT_F - mu * mu;
    rs[0] = mu;
    rs2[0] = rsqrtf(fmaxf(var, 0.0f) + 1e-5f);
  }
  __syncthreads();
  float mu = rs[0], inv = rs2[0];
  for (int j = tid; j < CONCAT_P; j += 256) {
    unsigned short o = (j < CONCAT_F) ? f2bfu((buf[j] - mu) * inv) : 0;
    comb[(long)row * CONCAT_P + j] = o;
  }
}

// ---------------- fc3: X @ w + b, 256 -> 1 ----------------------------------
__global__ void k_fc3(const float* __restrict__ X, const float* __restrict__ W,
                      const float* __restrict__ bias, float* __restrict__ out, int B) {
  int w = (int)((blockIdx.x * (long)blockDim.x + threadIdx.x) >> 6);
  int lane = threadIdx.x & 63;
  if (w >= B) return;
  float s = 0.0f;
#pragma unroll
  for (int j = 0; j < 4; ++j) s = fmaf(X[(long)w * 256 + lane + j * 64], W[lane + j * 64], s);
  for (int o = 32; o; o >>= 1) s += __shfl_down(s, o, 64);
  if (lane == 0) out[w] = s + bias[0];
}

// ---------------------------------------------------------------------------
extern "C" void kernel_launch(void* const* d_in, const int* in_sizes, int n_in,
                              void* d_out, int out_size, void* d_ws, size_t ws_size,
                              hipStream_t stream) {
  const float* drug_x = (const float*)d_in[0];
  const int* ei = (const int*)d_in[1];
  const int* batch = (const int*)d_in[2];
  const float* protein_x = (const float*)d_in[3];
  const float* fpp = (const float*)d_in[4];
  const float* W1 = (const float*)d_in[5];
  const float* b1 = (const float*)d_in[6];
  const float* W2 = (const float*)d_in[7];
  const float* b2 = (const float*)d_in[8];
  const float* W3 = (const float*)d_in[9];
  const float* b3 = (const float*)d_in[10];
  const float* Wd = (const float*)d_in[11];
  const float* bd = (const float*)d_in[12];
  const float* Wp = (const float*)d_in[13];
  const float* bp = (const float*)d_in[14];
  const float* Wf1 = (const float*)d_in[15];
  const float* bf1 = (const float*)d_in[16];
  const float* Wf2 = (const float*)d_in[17];
  const float* bf2 = (const float*)d_in[18];
  const float* Wf3 = (const float*)d_in[19];
  const float* bf3 = (const float*)d_in[20];
  float* out = (float*)d_out;

  const int N = in_sizes[0] / 30;
  const int E = in_sizes[1] / 2;
  const int B = in_sizes[4] / 881;

  // ---- GCN-phase workspace (4-byte words) ----
  int* rs = (int*)d_ws;
  float* dis = (float*)d_ws + ((size_t)N + 1);
  int* csr = (int*)d_ws + (2 * (size_t)N + 1);
  size_t oM = 2 * (size_t)N + 2 + (size_t)E;
  unsigned short* M = (unsigned short*)((float*)d_ws + oM);
  unsigned short* H = M + (size_t)N * 64;
  float* sums = (float*)d_ws + (oM + 64 * (size_t)N);
  float* cntf = sums + (size_t)B * 64;
  int* part = (int*)(cntf + B);
  unsigned short* protbh = (unsigned short*)(part + 1024);  // B*PROT_P bf16
  // ---- dense-tail aliases at offset 0 (GCN buffers dead by then) ----
  float* tail = (float*)d_ws;
  float* drug = tail;                                        // B*128 f32
  float* protP = drug + (size_t)B * 128;                     // 4*B*128 f32 partials
  unsigned short* combh = (unsigned short*)(protP + 4 * (size_t)B * 128);  // B*1152 bf16
  unsigned short* act1h = combh + (size_t)B * CONCAT_P;      // B*512 bf16
  float* act2 = (float*)(act1h + (size_t)B * 512);           // B*256 f32

  const int* srcIdx = ei;
  const int* dstIdx = ei + E;

  // ---- CSR build + degree ----
  hipMemsetAsync(rs, 0, ((size_t)N + 1) * sizeof(int), stream);
  k_count<<<(E + 255) / 256, 256, 0, stream>>>(dstIdx, rs, E);
  int NB = (N + 1023) / 1024;
  k_scan_p1<<<NB, 256, 0, stream>>>(rs, part, dis, N);  // + dis
  k_scan_p2<<<1, 1024, 0, stream>>>(part, NB);
  k_scan_p3<<<NB, 256, 0, stream>>>(rs, part, N);

  // ---- fat kernel: scatter || mm1 || protein-cvt (mutually independent) ----
  int EB = (E + 255) / 256;
  int mmBlocks = (N + 63) / 64;
  k_fat<<<EB + mmBlocks + B, 256, 0, stream>>>(
      srcIdx, dstIdx, rs, csr, E, EB,
      drug_x, W1, dis, M, N, mmBlocks,
      protein_x, protbh);

  // ---- GCN layers 2/3 + final gather ----
  int gWaves = (N + 3) / 4;
  int gBlocks = (gWaves + 3) / 4;
  k_gmm<<<mmBlocks, 256, 0, stream>>>(rs, csr, M, dis, b1, W2, H, N);  // H = M2
  k_gmm<<<mmBlocks, 256, 0, stream>>>(rs, csr, H, dis, b2, W3, M, N);  // M = M3
  k_gather_act<<<gBlocks, 256, 0, stream>>>(rs, csr, M, dis, b3, H, N);

  // ---- mean pool ----
  hipMemsetAsync(sums, 0, ((size_t)B * 64 + B) * sizeof(float), stream);
  int poolWaves = (N + 7) / 8;
  k_pool8<<<(poolWaves + 3) / 4, 256, 0, stream>>>(H, batch, sums, cntf, N);

  // ---- dense tail ----
  k_drugfc<<<B, 128, 0, stream>>>(sums, cntf, Wd, bd, drug, B);
  k_gemm2<true, float><<<dim3(B / 64, 1, 4), 256, 0, stream>>>(
      protbh, Wp, nullptr, protP, B, 128, PROT_K, PROT_P, 31, 8);
  k_concat_ln<<<B, 256, 0, stream>>>(drug, protP, bp, fpp, combh, B);
  k_gemm2<false, unsigned short><<<dim3(B / 64, 4, 1), 256, 0, stream>>>(
      combh, Wf1, bf1, act1h, B, 512, CONCAT_F, CONCAT_P, 36, 36);
  k_gemm2<false, float><<<dim3(B / 64, 2, 1), 256, 0, stream>>>(
      act1h, Wf2, bf2, act2, B, 256, 512, 512, 16, 16);
  k_fc3<<<(B + 3) / 4, 256, 0, stream>>>(act2, Wf3, bf3, out, B);
}

// Round 12
// 792.819 us; speedup vs baseline: 1.3275x; 1.1159x over previous
//
#include <hip/hip_runtime.h>
#include <hip/hip_bf16.h>

#define CONCAT_F 1137
#define CONCAT_P 1152  // padded to multiple of 32 for bf16 MFMA GEMM
#define PROT_K 979
#define PROT_P 992     // 979 padded to 31*32

typedef __attribute__((ext_vector_type(8))) short bf16x8;
typedef __attribute__((ext_vector_type(4))) float f32x4;

static __device__ __forceinline__ float bfu2f(unsigned short u) {
  return __uint_as_float(((unsigned)u) << 16);
}
static __device__ __forceinline__ unsigned short f2bfu(float v) {
  __hip_bfloat16 t = __float2bfloat16(v);
  unsigned short u;
  __builtin_memcpy(&u, &t, 2);
  return u;
}

// accumulate a bf16x4 row chunk (uint2) into 4 floats
#define ACC4(A0, A1, A2, A3, U)        \
  {                                    \
    A0 += bfu2f((U).x & 0xffffu);      \
    A1 += bfu2f((U).x >> 16);          \
    A2 += bfu2f((U).y & 0xffffu);      \
    A3 += bfu2f((U).y >> 16);          \
  }

// ================= XCD-partitioned CSR build =================
// Node classes: cls = d >> shift (8 ranges). Block handles class blockIdx&7;
// physical XCD = blockIdx%8 (m09/m157 heuristic) => each rs/csr window stays
// hot in ONE XCD's L2, so scattered 4B writes combine into full lines.
__global__ void k_count_xcd(const int* __restrict__ dst, int* __restrict__ rs,
                            int E, int shift, int chunk) {
  int cls = blockIdx.x & 7;
  int slice = blockIdx.x >> 3;
  int s0 = slice * chunk;
  int s1 = min(E, s0 + chunk);
  for (int e = s0 + threadIdx.x; e < s1; e += blockDim.x) {
    int d = dst[e];
    if ((d >> shift) == cls) atomicAdd(&rs[d], 1);
  }
}

__global__ void k_scatter_xcd(const int* __restrict__ src, const int* __restrict__ dst,
                              int* __restrict__ rs, int* __restrict__ csr,
                              int E, int shift, int chunk) {
  int cls = blockIdx.x & 7;
  int slice = blockIdx.x >> 3;
  int s0 = slice * chunk;
  int s1 = min(E, s0 + chunk);
  for (int e = s0 + threadIdx.x; e < s1; e += blockDim.x) {
    int d = dst[e];
    if ((d >> shift) == cls) {
      int pos = atomicAdd(&rs[d], 1);
      csr[pos] = src[e];
    }
  }
}

// block partial sums AND dis = rsqrt(1+cnt) (fused former k_disk)
__global__ void k_scan_p1(const int* __restrict__ cnt, int* __restrict__ part,
                          float* __restrict__ dis, int n) {
  __shared__ int red[256];
  int tid = threadIdx.x;
  long base = (long)blockIdx.x * 1024 + tid * 4;
  int s = 0;
#pragma unroll
  for (int i = 0; i < 4; ++i) {
    long j = base + i;
    if (j < n) {
      int c = cnt[j];
      s += c;
      dis[j] = rsqrtf(1.0f + (float)c);
    }
  }
  red[tid] = s;
  __syncthreads();
  for (int off = 128; off; off >>= 1) {
    if (tid < off) red[tid] += red[tid + off];
    __syncthreads();
  }
  if (tid == 0) part[blockIdx.x] = red[0];
}

__global__ void k_scan_p2(int* __restrict__ part, int nb) {
  __shared__ int a[1024], b_[1024];
  int t = threadIdx.x;
  a[t] = (t < nb) ? part[t] : 0;
  __syncthreads();
  int* s = a;
  int* d = b_;
  for (int off = 1; off < 1024; off <<= 1) {
    d[t] = s[t] + ((t >= off) ? s[t - off] : 0);
    __syncthreads();
    int* tmp = s;
    s = d;
    d = tmp;
  }
  if (t < nb) part[t] = (t == 0) ? 0 : s[t - 1];  // exclusive
}

__global__ void k_scan_p3(int* __restrict__ rs, const int* __restrict__ part, int n) {
  __shared__ int a[256], b_[256];
  int tid = threadIdx.x;
  long base = (long)blockIdx.x * 1024 + tid * 4;
  int v[4];
#pragma unroll
  for (int i = 0; i < 4; ++i) {
    long j = base + i;
    v[i] = (j < n) ? rs[j] : 0;
  }
  a[tid] = v[0] + v[1] + v[2] + v[3];
  __syncthreads();
  int* s = a;
  int* d = b_;
  for (int off = 1; off < 256; off <<= 1) {
    d[tid] = s[tid] + ((tid >= off) ? s[tid - off] : 0);
    __syncthreads();
    int* t2 = s;
    s = d;
    d = t2;
  }
  int run = part[blockIdx.x] + ((tid == 0) ? 0 : s[tid - 1]);
#pragma unroll
  for (int i = 0; i < 4; ++i) {
    long j = base + i;
    if (j < n) {
      rs[j] = run;
      run += v[i];
    }
  }
}

// ====== GCN layer-1 matmul: M = dis*(X@W), f32 in, bf16 out (K=30) =========
template <int K, bool ACT>
__global__ __launch_bounds__(256) void k_mm(const void* __restrict__ Xv,
                                            const float* __restrict__ W,
                                            const float* __restrict__ bprev,
                                            const float* __restrict__ dis,
                                            unsigned short* __restrict__ M, int n) {
  __shared__ __align__(16) float hT[K][68];
  __shared__ __align__(16) float Ws[K * 64];
  __shared__ float disS[64];
  int tid = threadIdx.x;
  int rb = blockIdx.x * 64;
  for (int j = tid; j < K * 16; j += 256) ((float4*)Ws)[j] = ((const float4*)W)[j];
  if (tid < 64) disS[tid] = (rb + tid < n) ? dis[rb + tid] : 0.0f;
  __syncthreads();
  if constexpr (ACT) {
    const unsigned short* X = (const unsigned short*)Xv;
    int k = tid & 63;
    float bk = bprev[k];
#pragma unroll
    for (int r = tid >> 6; r < 64; r += 4) {
      float h = 0.0f;
      if (rb + r < n) {
        float raw = bfu2f(X[(long)(rb + r) * 64 + k]);
        h = fmaxf(fmaf(raw, disS[r], bk), 0.0f);
      }
      hT[k][r] = h;
    }
  } else {
    const float* X = (const float*)Xv;
    for (int idx = tid; idx < 64 * K; idx += 256) {
      int r = idx / K, k = idx - r * K;
      hT[k][r] = (rb + r < n) ? X[(long)(rb + r) * K + k] : 0.0f;
    }
  }
  __syncthreads();
  int rt = (tid & 15) * 4;
  int ct = (tid >> 4) * 4;
  float acc[4][4] = {};
#pragma unroll 5
  for (int k = 0; k < K; ++k) {
    float4 xr = *(const float4*)&hT[k][rt];
    float4 wr = *(const float4*)&Ws[k * 64 + ct];
    float xa[4] = {xr.x, xr.y, xr.z, xr.w};
    float wa[4] = {wr.x, wr.y, wr.z, wr.w};
#pragma unroll
    for (int i = 0; i < 4; ++i)
#pragma unroll
      for (int j = 0; j < 4; ++j) acc[i][j] = fmaf(xa[i], wa[j], acc[i][j]);
  }
#pragma unroll
  for (int i = 0; i < 4; ++i) {
    int row = rb + rt + i;
    if (row >= n) break;
    float dv = disS[rt + i];
    ushort4 pk;
    pk.x = f2bfu(acc[i][0] * dv);
    pk.y = f2bfu(acc[i][1] * dv);
    pk.z = f2bfu(acc[i][2] * dv);
    pk.w = f2bfu(acc[i][3] * dv);
    *(ushort4*)&M[(long)row * 64 + ct] = pk;
  }
}

// ---- 4-edge-unrolled row aggregation body (16 lanes x uint2 per row) -------
static __device__ __forceinline__ void gather_rows(
    const int* __restrict__ rs, const int* __restrict__ csr,
    const unsigned short* __restrict__ Min, int node, int l16,
    float& A0, float& A1, float& A2, float& A3) {
  float a0, a1, a2, a3;
  float b0 = 0.f, b1 = 0.f, b2 = 0.f, b3 = 0.f;
  float c0 = 0.f, c1 = 0.f, c2 = 0.f, c3 = 0.f;
  float d0 = 0.f, d1 = 0.f, d2 = 0.f, d3 = 0.f;
  uint2 v = *(const uint2*)(Min + (size_t)node * 64 + l16 * 4);  // self loop
  a0 = bfu2f(v.x & 0xffffu);
  a1 = bfu2f(v.x >> 16);
  a2 = bfu2f(v.y & 0xffffu);
  a3 = bfu2f(v.y >> 16);
  int start = (node == 0) ? 0 : rs[node - 1];
  int end = rs[node];
  int j = start;
  for (; j + 3 < end; j += 4) {
    int s0 = csr[j], s1 = csr[j + 1], s2 = csr[j + 2], s3 = csr[j + 3];
    uint2 u0 = *(const uint2*)(Min + (size_t)s0 * 64 + l16 * 4);
    uint2 u1 = *(const uint2*)(Min + (size_t)s1 * 64 + l16 * 4);
    uint2 u2 = *(const uint2*)(Min + (size_t)s2 * 64 + l16 * 4);
    uint2 u3 = *(const uint2*)(Min + (size_t)s3 * 64 + l16 * 4);
    ACC4(a0, a1, a2, a3, u0);
    ACC4(b0, b1, b2, b3, u1);
    ACC4(c0, c1, c2, c3, u2);
    ACC4(d0, d1, d2, d3, u3);
  }
  if (j + 1 < end) {
    int s0 = csr[j], s1 = csr[j + 1];
    uint2 u0 = *(const uint2*)(Min + (size_t)s0 * 64 + l16 * 4);
    uint2 u1 = *(const uint2*)(Min + (size_t)s1 * 64 + l16 * 4);
    ACC4(a0, a1, a2, a3, u0);
    ACC4(b0, b1, b2, b3, u1);
    j += 2;
  }
  if (j < end) {
    uint2 u0 = *(const uint2*)(Min + (size_t)csr[j] * 64 + l16 * 4);
    ACC4(a0, a1, a2, a3, u0);
  }
  A0 = (a0 + b0) + (c0 + d0);
  A1 = (a1 + b1) + (c1 + d1);
  A2 = (a2 + b2) + (c2 + d2);
  A3 = (a3 + b3) + (c3 + d3);
}

// ===== fused gather+act+MFMA: Mout = dis * (relu((agg Min)*dis + b) @ W) ====
__global__ __launch_bounds__(256) void k_gmm(
    const int* __restrict__ rs, const int* __restrict__ csr,
    const unsigned short* __restrict__ Min, const float* __restrict__ dis,
    const float* __restrict__ bias, const float* __restrict__ W,
    unsigned short* __restrict__ Mout, int n) {
  __shared__ __align__(16) unsigned short As[64 * 64];
  __shared__ __align__(16) unsigned short Bt[64 * 64];
  const int tid = threadIdx.x;
  const int bm = blockIdx.x * 64;
  // ---- stage Bt[n][k] = W[k][n] bf16, swizzled
  {
    int nn = tid & 63, k0 = (tid >> 6) * 16;
    bf16x8 v0, v1;
#pragma unroll
    for (int i = 0; i < 8; ++i) v0[i] = (short)f2bfu(W[(size_t)(k0 + i) * 64 + nn]);
#pragma unroll
    for (int i = 0; i < 8; ++i) v1[i] = (short)f2bfu(W[(size_t)(k0 + 8 + i) * 64 + nn]);
    int off0 = (nn * 128 + k0 * 2) ^ ((nn & 7) << 4);
    int off1 = (nn * 128 + (k0 + 8) * 2) ^ ((nn & 7) << 4);
    *(bf16x8*)((char*)Bt + off0) = v0;
    *(bf16x8*)((char*)Bt + off1) = v1;
  }
  // ---- gather + act into As
  const int lane = tid & 63;
  const int wv = tid >> 6;
  const int grp = lane >> 4, l16 = lane & 15;
  const float4 bb = *(const float4*)(bias + l16 * 4);
  for (int p = 0; p < 4; ++p) {
    int local = wv * 16 + p * 4 + grp;
    int node = bm + local;
    float A0 = 0.f, A1 = 0.f, A2 = 0.f, A3 = 0.f, dv = 0.f;
    if (node < n) {
      gather_rows(rs, csr, Min, node, l16, A0, A1, A2, A3);
      dv = dis[node];
    }
    ushort4 h;
    h.x = f2bfu(fmaxf(fmaf(A0, dv, bb.x), 0.f));
    h.y = f2bfu(fmaxf(fmaf(A1, dv, bb.y), 0.f));
    h.z = f2bfu(fmaxf(fmaf(A2, dv, bb.z), 0.f));
    h.w = f2bfu(fmaxf(fmaf(A3, dv, bb.w), 0.f));
    int off = (local * 128 + l16 * 8) ^ ((local & 7) << 4);
    *(ushort4*)((char*)As + off) = h;
  }
  __syncthreads();
  // ---- MFMA phase
  const int kb = lane >> 4, fr = lane & 15;
  f32x4 acc[4];
#pragma unroll
  for (int i = 0; i < 4; ++i) acc[i] = f32x4{0.f, 0.f, 0.f, 0.f};
  const int ar = wv * 16 + fr;
#pragma unroll
  for (int kc = 0; kc < 2; ++kc) {
    int aoff = (ar * 128 + kc * 64 + kb * 16) ^ ((ar & 7) << 4);
    bf16x8 a = *(const bf16x8*)((char*)As + aoff);
#pragma unroll
    for (int ni = 0; ni < 4; ++ni) {
      int nr = ni * 16 + fr;
      int boff = (nr * 128 + kc * 64 + kb * 16) ^ ((nr & 7) << 4);
      bf16x8 b = *(const bf16x8*)((char*)Bt + boff);
      acc[ni] = __builtin_amdgcn_mfma_f32_16x16x32_bf16(a, b, acc[ni], 0, 0, 0);
    }
  }
#pragma unroll
  for (int r = 0; r < 4; ++r) {
    int row = bm + wv * 16 + kb * 4 + r;
    if (row < n) {
      float dvo = dis[row];
#pragma unroll
      for (int ni = 0; ni < 4; ++ni)
        Mout[(size_t)row * 64 + ni * 16 + fr] = f2bfu(acc[ni][r] * dvo);
    }
  }
}

// == gather+act: H[d] = relu((M[d] + sum_{s in csr[d]} M[s]) * dis[d] + b) ==
__global__ void k_gather_act(const int* __restrict__ rs, const int* __restrict__ csr,
                             const unsigned short* __restrict__ M,
                             const float* __restrict__ dis, const float* __restrict__ bias,
                             unsigned short* __restrict__ H, int n) {
  int w = (int)((blockIdx.x * (long)blockDim.x + threadIdx.x) >> 6);
  int lane = threadIdx.x & 63;
  int grp = lane >> 4, l16 = lane & 15;
  int node = w * 4 + grp;
  if (node >= n) return;
  float A0, A1, A2, A3;
  gather_rows(rs, csr, M, node, l16, A0, A1, A2, A3);
  float dv = dis[node];
  float4 bb = *(const float4*)(bias + l16 * 4);
  ushort4 o;
  o.x = f2bfu(fmaxf(fmaf(A0, dv, bb.x), 0.f));
  o.y = f2bfu(fmaxf(fmaf(A1, dv, bb.y), 0.f));
  o.z = f2bfu(fmaxf(fmaf(A2, dv, bb.z), 0.f));
  o.w = f2bfu(fmaxf(fmaf(A3, dv, bb.w), 0.f));
  *(ushort4*)(H + (size_t)node * 64 + l16 * 4) = o;
}

// ============ mean pool over sorted batch (H already post-relu) =============
__global__ void k_pool8(const unsigned short* __restrict__ H, const int* __restrict__ batch,
                        float* __restrict__ sums, float* __restrict__ cntf, int n) {
  int w = (int)((blockIdx.x * (long)blockDim.x + threadIdx.x) >> 6);
  int lane = threadIdx.x & 63;
  int r0 = w * 8;
  if (r0 >= n) return;
  int cur = batch[r0];
  float acc = bfu2f(H[(long)r0 * 64 + lane]);
  float c = 1.0f;
  for (int i = 1; i < 8; ++i) {
    int r = r0 + i;
    if (r >= n) break;
    int b = batch[r];
    float v = bfu2f(H[(long)r * 64 + lane]);
    if (b == cur) {
      acc += v;
      c += 1.0f;
    } else {
      unsafeAtomicAdd(&sums[(long)cur * 64 + lane], acc);
      if (lane == 0) unsafeAtomicAdd(&cntf[cur], c);
      cur = b;
      acc = v;
      c = 1.0f;
    }
  }
  unsafeAtomicAdd(&sums[(long)cur * 64 + lane], acc);
  if (lane == 0) unsafeAtomicAdd(&cntf[cur], c);
}

// ================= drug fc: relu((sums/cnt) @ Wd + bd), 64 -> 128 ===========
__global__ void k_drugfc(const float* __restrict__ sums, const float* __restrict__ cnt,
                         const float* __restrict__ W, const float* __restrict__ b,
                         float* __restrict__ out, int B) {
  __shared__ float ps[64];
  int row = blockIdx.x;
  int tid = threadIdx.x;
  float inv = 1.0f / fmaxf(cnt[row], 1.0f);
  if (tid < 64) ps[tid] = sums[(long)row * 64 + tid] * inv;
  __syncthreads();
  float acc = b[tid];
#pragma unroll 8
  for (int k = 0; k < 64; ++k) acc = fmaf(ps[k], W[k * 128 + tid], acc);
  out[(long)row * 128 + tid] = fmaxf(acc, 0.0f);
}

// ============ f32 [M x Kin] -> bf16 [M x ldout], zero-padded cols ===========
__global__ void k_cvt_bf16(const float* __restrict__ X, unsigned short* __restrict__ Y,
                           int Kin, int ldout) {
  int row = blockIdx.x;
  const float* xr = X + (size_t)row * Kin;
  unsigned short* yr = Y + (size_t)row * ldout;
  for (int j = threadIdx.x; j < ldout; j += 256)
    yr[j] = (j < Kin) ? f2bfu(xr[j]) : 0;
}

// ===== bf16 MFMA GEMM, 64x128 tile, BK=32, reg-prefetch double-buffer ======
template <bool SPLIT, typename OT>
__global__ __launch_bounds__(256, 3) void k_gemm2(
    const unsigned short* __restrict__ A, const float* __restrict__ W,
    const float* __restrict__ bias, OT* __restrict__ C,
    int Mrows, int N, int K, int lda, int nsteps, int chunkSteps) {
  __shared__ __align__(16) unsigned short As[2][64 * 32];
  __shared__ __align__(16) unsigned short Bs[2][128 * 32];
  const int tid = threadIdx.x;
  const int lane = tid & 63;
  const int wid = tid >> 6;
  const int bm = blockIdx.x * 64;
  const int bn = blockIdx.y * 128;
  const int kb = lane >> 4, fr = lane & 15;
  const int ss0 = blockIdx.z * chunkSteps;
  const int ss1 = min(nsteps, ss0 + chunkSteps);

  f32x4 acc[8];
#pragma unroll
  for (int j = 0; j < 8; ++j) acc[j] = f32x4{0.f, 0.f, 0.f, 0.f};

  const int ar = wid * 16 + fr;
  const int aOff = (ar * 64 + kb * 16) ^ ((ar & 7) << 4);
  int bOff[8];
#pragma unroll
  for (int ni = 0; ni < 8; ++ni) {
    int nr = ni * 16 + fr;
    bOff[ni] = (nr * 64 + kb * 16) ^ ((nr & 7) << 4);
  }
  const int arow = tid >> 2, ac = tid & 3;
  const int aW = (arow * 64 + ac * 16) ^ ((arow & 7) << 4);
  const int bn_ = tid & 127, bk0 = (tid >> 7) * 2;
  int bW[2];
#pragma unroll
  for (int p = 0; p < 2; ++p) {
    int kbb = bk0 + p;
    bW[p] = (bn_ * 64 + kbb * 16) ^ ((bn_ & 7) << 4);
  }

  bf16x8 pa;
  float pb[2][8];
  const unsigned short* aptr = A + (size_t)(bm + arow) * lda + ac * 8;

#define LOAD_STEP(S)                                              \
  {                                                               \
    int k0 = (S) * 32;                                            \
    pa = *(const bf16x8*)(aptr + k0);                             \
    _Pragma("unroll") for (int p = 0; p < 2; ++p) {               \
      _Pragma("unroll") for (int i = 0; i < 8; ++i) {             \
        int gk = k0 + (bk0 + p) * 8 + i;                          \
        pb[p][i] = (gk < K) ? W[(size_t)gk * N + bn + bn_] : 0.f; \
      }                                                           \
    }                                                             \
  }
#define STORE_STEP(BUF)                                           \
  {                                                               \
    *(bf16x8*)((char*)As[BUF] + aW) = pa;                         \
    _Pragma("unroll") for (int p = 0; p < 2; ++p) {               \
      bf16x8 v;                                                   \
      _Pragma("unroll") for (int i = 0; i < 8; ++i)               \
          v[i] = (short)f2bfu(pb[p][i]);                          \
      *(bf16x8*)((char*)Bs[BUF] + bW[p]) = v;                     \
    }                                                             \
  }

  LOAD_STEP(ss0);
  STORE_STEP(0);
  __syncthreads();
  int cur = 0;
  for (int s = ss0; s < ss1; ++s) {
    bool more = (s + 1 < ss1);
    if (more) LOAD_STEP(s + 1);
    bf16x8 a0 = *(const bf16x8*)((char*)As[cur] + aOff);
#pragma unroll
    for (int ni = 0; ni < 8; ++ni) {
      bf16x8 b = *(const bf16x8*)((char*)Bs[cur] + bOff[ni]);
      acc[ni] = __builtin_amdgcn_mfma_f32_16x16x32_bf16(a0, b, acc[ni], 0, 0, 0);
    }
    if (more) {
      STORE_STEP(cur ^ 1);
      __syncthreads();
      cur ^= 1;
    }
  }
  if constexpr (SPLIT) {
    float* Cz = (float*)C + (size_t)blockIdx.z * Mrows * N;
#pragma unroll
    for (int ni = 0; ni < 8; ++ni)
#pragma unroll
      for (int r = 0; r < 4; ++r) {
        int row = bm + wid * 16 + kb * 4 + r;
        int col = bn + ni * 16 + fr;
        Cz[(size_t)row * N + col] = acc[ni][r];
      }
  } else {
    float bv[8];
#pragma unroll
    for (int ni = 0; ni < 8; ++ni) bv[ni] = bias[bn + ni * 16 + fr];
#pragma unroll
    for (int ni = 0; ni < 8; ++ni)
#pragma unroll
      for (int r = 0; r < 4; ++r) {
        int row = bm + wid * 16 + kb * 4 + r;
        int col = bn + ni * 16 + fr;
        float x = fmaxf(acc[ni][r] + bv[ni], 0.f);
        if constexpr (__hip_internal::is_same<OT, float>::value) {
          C[(size_t)row * N + col] = x;
        } else {
          C[(size_t)row * N + col] = f2bfu(x);
        }
      }
  }
#undef LOAD_STEP
#undef STORE_STEP
}

// ---- concat + LayerNorm; prot = relu(sum of 4 K-split partials + bp) -------
__global__ void k_concat_ln(const float* __restrict__ drug, const float* __restrict__ protP,
                            const float* __restrict__ bp, const float* __restrict__ fpp,
                            unsigned short* __restrict__ comb, int B) {
  __shared__ float buf[CONCAT_F];
  __shared__ float rs[4], rs2[4];
  int row = blockIdx.x;
  int tid = threadIdx.x;
  const size_t MN = (size_t)B * 128;
  float s = 0.0f, s2 = 0.0f;
  for (int j = tid; j < CONCAT_F; j += 256) {
    float v;
    if (j < 128) {
      v = drug[(long)row * 128 + j];
    } else if (j < 256) {
      int c = j - 128;
      size_t o = (size_t)row * 128 + c;
      float acc = protP[o] + protP[MN + o] + protP[2 * MN + o] + protP[3 * MN + o];
      v = fmaxf(acc + bp[c], 0.0f);
    } else {
      v = fpp[(long)row * 881 + (j - 256)];
    }
    buf[j] = v;
    s += v;
    s2 += v * v;
  }
  for (int o = 32; o; o >>= 1) {
    s += __shfl_down(s, o, 64);
    s2 += __shfl_down(s2, o, 64);
  }
  int lane = tid & 63, wid = tid >> 6;
  if (lane == 0) { rs[wid] = s; rs2[wid] = s2; }
  __syncthreads();
  if (tid == 0) {
    float ts = rs[0] + rs[1] + rs[2] + rs[3];
    float ts2 = rs2[0] + rs2[1] + rs2[2] + rs2[3];
    float mu = ts / (float)CONCAT_F;
    float var = ts2 / (float)CONCAT_F - mu * mu;
    rs[0] = mu;
    rs2[0] = rsqrtf(fmaxf(var, 0.0f) + 1e-5f);
  }
  __syncthreads();
  float mu = rs[0], inv = rs2[0];
  for (int j = tid; j < CONCAT_P; j += 256) {
    unsigned short o = (j < CONCAT_F) ? f2bfu((buf[j] - mu) * inv) : 0;
    comb[(long)row * CONCAT_P + j] = o;
  }
}

// ---------------- fc3: X @ w + b, 256 -> 1 ----------------------------------
__global__ void k_fc3(const float* __restrict__ X, const float* __restrict__ W,
                      const float* __restrict__ bias, float* __restrict__ out, int B) {
  int w = (int)((blockIdx.x * (long)blockDim.x + threadIdx.x) >> 6);
  int lane = threadIdx.x & 63;
  if (w >= B) return;
  float s = 0.0f;
#pragma unroll
  for (int j = 0; j < 4; ++j) s = fmaf(X[(long)w * 256 + lane + j * 64], W[lane + j * 64], s);
  for (int o = 32; o; o >>= 1) s += __shfl_down(s, o, 64);
  if (lane == 0) out[w] = s + bias[0];
}

// ---------------------------------------------------------------------------
extern "C" void kernel_launch(void* const* d_in, const int* in_sizes, int n_in,
                              void* d_out, int out_size, void* d_ws, size_t ws_size,
                              hipStream_t stream) {
  const float* drug_x = (const float*)d_in[0];
  const int* ei = (const int*)d_in[1];
  const int* batch = (const int*)d_in[2];
  const float* protein_x = (const float*)d_in[3];
  const float* fpp = (const float*)d_in[4];
  const float* W1 = (const float*)d_in[5];
  const float* b1 = (const float*)d_in[6];
  const float* W2 = (const float*)d_in[7];
  const float* b2 = (const float*)d_in[8];
  const float* W3 = (const float*)d_in[9];
  const float* b3 = (const float*)d_in[10];
  const float* Wd = (const float*)d_in[11];
  const float* bd = (const float*)d_in[12];
  const float* Wp = (const float*)d_in[13];
  const float* bp = (const float*)d_in[14];
  const float* Wf1 = (const float*)d_in[15];
  const float* bf1 = (const float*)d_in[16];
  const float* Wf2 = (const float*)d_in[17];
  const float* bf2 = (const float*)d_in[18];
  const float* Wf3 = (const float*)d_in[19];
  const float* bf3 = (const float*)d_in[20];
  float* out = (float*)d_out;

  const int N = in_sizes[0] / 30;
  const int E = in_sizes[1] / 2;
  const int B = in_sizes[4] / 881;

  // ---- GCN-phase workspace (4-byte words) ----
  int* rs = (int*)d_ws;
  float* dis = (float*)d_ws + ((size_t)N + 1);
  int* csr = (int*)d_ws + (2 * (size_t)N + 1);
  size_t oM = 2 * (size_t)N + 2 + (size_t)E;
  unsigned short* M = (unsigned short*)((float*)d_ws + oM);
  unsigned short* H = M + (size_t)N * 64;
  float* sums = (float*)d_ws + (oM + 64 * (size_t)N);
  float* cntf = sums + (size_t)B * 64;
  int* part = (int*)(cntf + B);
  unsigned short* protbh = (unsigned short*)(part + 1024);  // B*PROT_P bf16
  // ---- dense-tail aliases at offset 0 (GCN buffers dead by then) ----
  float* tail = (float*)d_ws;
  float* drug = tail;                                        // B*128 f32
  float* protP = drug + (size_t)B * 128;                     // 4*B*128 f32 partials
  unsigned short* combh = (unsigned short*)(protP + 4 * (size_t)B * 128);  // B*1152 bf16
  unsigned short* act1h = combh + (size_t)B * CONCAT_P;      // B*512 bf16
  float* act2 = (float*)(act1h + (size_t)B * 512);           // B*256 f32

  const int* srcIdx = ei;
  const int* dstIdx = ei + E;

  // node-class shift: (N-1)>>shift <= 7  -> 8 contiguous node ranges
  int shift = 0;
  while (((N - 1) >> shift) > 7) ++shift;
  const int CHUNK = 2048;
  int G = (E + CHUNK - 1) / CHUNK;

  // ---- protein f32 -> bf16 ----
  k_cvt_bf16<<<B, 256, 0, stream>>>(protein_x, protbh, PROT_K, PROT_P);

  // ---- CSR build + degree (XCD-partitioned count/scatter) ----
  hipMemsetAsync(rs, 0, ((size_t)N + 1) * sizeof(int), stream);
  k_count_xcd<<<8 * G, 256, 0, stream>>>(dstIdx, rs, E, shift, CHUNK);
  int NB = (N + 1023) / 1024;
  k_scan_p1<<<NB, 256, 0, stream>>>(rs, part, dis, N);  // + dis
  k_scan_p2<<<1, 1024, 0, stream>>>(part, NB);
  k_scan_p3<<<NB, 256, 0, stream>>>(rs, part, N);
  k_scatter_xcd<<<8 * G, 256, 0, stream>>>(srcIdx, dstIdx, rs, csr, E, shift, CHUNK);

  // ---- GCN layers ----
  int mmBlocks = (N + 63) / 64;
  int gWaves = (N + 3) / 4;
  int gBlocks = (gWaves + 3) / 4;
  k_mm<30, false><<<mmBlocks, 256, 0, stream>>>(drug_x, W1, nullptr, dis, M, N);
  k_gmm<<<mmBlocks, 256, 0, stream>>>(rs, csr, M, dis, b1, W2, H, N);  // H = M2
  k_gmm<<<mmBlocks, 256, 0, stream>>>(rs, csr, H, dis, b2, W3, M, N);  // M = M3
  k_gather_act<<<gBlocks, 256, 0, stream>>>(rs, csr, M, dis, b3, H, N);

  // ---- mean pool ----
  hipMemsetAsync(sums, 0, ((size_t)B * 64 + B) * sizeof(float), stream);
  int poolWaves = (N + 7) / 8;
  k_pool8<<<(poolWaves + 3) / 4, 256, 0, stream>>>(H, batch, sums, cntf, N);

  // ---- dense tail ----
  k_drugfc<<<B, 128, 0, stream>>>(sums, cntf, Wd, bd, drug, B);
  k_gemm2<true, float><<<dim3(B / 64, 1, 4), 256, 0, stream>>>(
      protbh, Wp, nullptr, protP, B, 128, PROT_K, PROT_P, 31, 8);
  k_concat_ln<<<B, 256, 0, stream>>>(drug, protP, bp, fpp, combh, B);
  k_gemm2<false, unsigned short><<<dim3(B / 64, 4, 1), 256, 0, stream>>>(
      combh, Wf1, bf1, act1h, B, 512, CONCAT_F, CONCAT_P, 36, 36);
  k_gemm2<false, float><<<dim3(B / 64, 2, 1), 256, 0, stream>>>(
      act1h, Wf2, bf2, act2, B, 256, 512, 512, 16, 16);
  k_fc3<<<(B + 3) / 4, 256, 0, stream>>>(act2, Wf3, bf3, out, B);
}

// Round 13
// 785.652 us; speedup vs baseline: 1.3397x; 1.0091x over previous
//
#include <hip/hip_runtime.h>
#include <hip/hip_bf16.h>

#define CONCAT_F 1137
#define CONCAT_P 1152  // padded to multiple of 32 for bf16 MFMA GEMM
#define PROT_K 979
#define PROT_P 992     // 979 padded to 31*32

typedef __attribute__((ext_vector_type(8))) short bf16x8;
typedef __attribute__((ext_vector_type(4))) float f32x4;

static __device__ __forceinline__ float bfu2f(unsigned short u) {
  return __uint_as_float(((unsigned)u) << 16);
}
static __device__ __forceinline__ unsigned short f2bfu(float v) {
  __hip_bfloat16 t = __float2bfloat16(v);
  unsigned short u;
  __builtin_memcpy(&u, &t, 2);
  return u;
}

// accumulate a bf16x4 row chunk (uint2) into 4 floats
#define ACC4(A0, A1, A2, A3, U)        \
  {                                    \
    A0 += bfu2f((U).x & 0xffffu);      \
    A1 += bfu2f((U).x >> 16);          \
    A2 += bfu2f((U).y & 0xffffu);      \
    A3 += bfu2f((U).y >> 16);          \
  }

// ================= XCD-partitioned CSR build =================
__global__ void k_count_xcd(const int* __restrict__ dst, int* __restrict__ rs,
                            int E, int shift, int chunk) {
  int cls = blockIdx.x & 7;
  int slice = blockIdx.x >> 3;
  int s0 = slice * chunk;
  int s1 = min(E, s0 + chunk);
  for (int e = s0 + threadIdx.x; e < s1; e += blockDim.x) {
    int d = dst[e];
    if ((d >> shift) == cls) atomicAdd(&rs[d], 1);
  }
}

__global__ void k_scatter_xcd(const int* __restrict__ src, const int* __restrict__ dst,
                              int* __restrict__ rs, int* __restrict__ csr,
                              int E, int shift, int chunk) {
  int cls = blockIdx.x & 7;
  int slice = blockIdx.x >> 3;
  int s0 = slice * chunk;
  int s1 = min(E, s0 + chunk);
  for (int e = s0 + threadIdx.x; e < s1; e += blockDim.x) {
    int d = dst[e];
    if ((d >> shift) == cls) {
      int pos = atomicAdd(&rs[d], 1);
      csr[pos] = src[e];
    }
  }
}

// block partial sums AND dis = rsqrt(1+cnt)
__global__ void k_scan_p1(const int* __restrict__ cnt, int* __restrict__ part,
                          float* __restrict__ dis, int n) {
  __shared__ int red[256];
  int tid = threadIdx.x;
  long base = (long)blockIdx.x * 1024 + tid * 4;
  int s = 0;
#pragma unroll
  for (int i = 0; i < 4; ++i) {
    long j = base + i;
    if (j < n) {
      int c = cnt[j];
      s += c;
      dis[j] = rsqrtf(1.0f + (float)c);
    }
  }
  red[tid] = s;
  __syncthreads();
  for (int off = 128; off; off >>= 1) {
    if (tid < off) red[tid] += red[tid + off];
    __syncthreads();
  }
  if (tid == 0) part[blockIdx.x] = red[0];
}

__global__ void k_scan_p2(int* __restrict__ part, int nb) {
  __shared__ int a[1024], b_[1024];
  int t = threadIdx.x;
  a[t] = (t < nb) ? part[t] : 0;
  __syncthreads();
  int* s = a;
  int* d = b_;
  for (int off = 1; off < 1024; off <<= 1) {
    d[t] = s[t] + ((t >= off) ? s[t - off] : 0);
    __syncthreads();
    int* tmp = s;
    s = d;
    d = tmp;
  }
  if (t < nb) part[t] = (t == 0) ? 0 : s[t - 1];  // exclusive
}

__global__ void k_scan_p3(int* __restrict__ rs, const int* __restrict__ part, int n) {
  __shared__ int a[256], b_[256];
  int tid = threadIdx.x;
  long base = (long)blockIdx.x * 1024 + tid * 4;
  int v[4];
#pragma unroll
  for (int i = 0; i < 4; ++i) {
    long j = base + i;
    v[i] = (j < n) ? rs[j] : 0;
  }
  a[tid] = v[0] + v[1] + v[2] + v[3];
  __syncthreads();
  int* s = a;
  int* d = b_;
  for (int off = 1; off < 256; off <<= 1) {
    d[tid] = s[tid] + ((tid >= off) ? s[tid - off] : 0);
    __syncthreads();
    int* t2 = s;
    s = d;
    d = t2;
  }
  int run = part[blockIdx.x] + ((tid == 0) ? 0 : s[tid - 1]);
#pragma unroll
  for (int i = 0; i < 4; ++i) {
    long j = base + i;
    if (j < n) {
      rs[j] = run;
      run += v[i];
    }
  }
}

// ====== GCN layer-1 matmul: M = dis*(X@W), f32 in, bf16 out (K=30) =========
template <int K, bool ACT>
__global__ __launch_bounds__(256) void k_mm(const void* __restrict__ Xv,
                                            const float* __restrict__ W,
                                            const float* __restrict__ bprev,
                                            const float* __restrict__ dis,
                                            unsigned short* __restrict__ M, int n) {
  __shared__ __align__(16) float hT[K][68];
  __shared__ __align__(16) float Ws[K * 64];
  __shared__ float disS[64];
  int tid = threadIdx.x;
  int rb = blockIdx.x * 64;
  for (int j = tid; j < K * 16; j += 256) ((float4*)Ws)[j] = ((const float4*)W)[j];
  if (tid < 64) disS[tid] = (rb + tid < n) ? dis[rb + tid] : 0.0f;
  __syncthreads();
  if constexpr (ACT) {
    const unsigned short* X = (const unsigned short*)Xv;
    int k = tid & 63;
    float bk = bprev[k];
#pragma unroll
    for (int r = tid >> 6; r < 64; r += 4) {
      float h = 0.0f;
      if (rb + r < n) {
        float raw = bfu2f(X[(long)(rb + r) * 64 + k]);
        h = fmaxf(fmaf(raw, disS[r], bk), 0.0f);
      }
      hT[k][r] = h;
    }
  } else {
    const float* X = (const float*)Xv;
    for (int idx = tid; idx < 64 * K; idx += 256) {
      int r = idx / K, k = idx - r * K;
      hT[k][r] = (rb + r < n) ? X[(long)(rb + r) * K + k] : 0.0f;
    }
  }
  __syncthreads();
  int rt = (tid & 15) * 4;
  int ct = (tid >> 4) * 4;
  float acc[4][4] = {};
#pragma unroll 5
  for (int k = 0; k < K; ++k) {
    float4 xr = *(const float4*)&hT[k][rt];
    float4 wr = *(const float4*)&Ws[k * 64 + ct];
    float xa[4] = {xr.x, xr.y, xr.z, xr.w};
    float wa[4] = {wr.x, wr.y, wr.z, wr.w};
#pragma unroll
    for (int i = 0; i < 4; ++i)
#pragma unroll
      for (int j = 0; j < 4; ++j) acc[i][j] = fmaf(xa[i], wa[j], acc[i][j]);
  }
#pragma unroll
  for (int i = 0; i < 4; ++i) {
    int row = rb + rt + i;
    if (row >= n) break;
    float dv = disS[rt + i];
    ushort4 pk;
    pk.x = f2bfu(acc[i][0] * dv);
    pk.y = f2bfu(acc[i][1] * dv);
    pk.z = f2bfu(acc[i][2] * dv);
    pk.w = f2bfu(acc[i][3] * dv);
    *(ushort4*)&M[(long)row * 64 + ct] = pk;
  }
}

// ---- 4-edge-unrolled row aggregation body (16 lanes x uint2 per row) -------
static __device__ __forceinline__ void gather_rows(
    const int* __restrict__ rs, const int* __restrict__ csr,
    const unsigned short* __restrict__ Min, int node, int l16,
    float& A0, float& A1, float& A2, float& A3) {
  float a0, a1, a2, a3;
  float b0 = 0.f, b1 = 0.f, b2 = 0.f, b3 = 0.f;
  float c0 = 0.f, c1 = 0.f, c2 = 0.f, c3 = 0.f;
  float d0 = 0.f, d1 = 0.f, d2 = 0.f, d3 = 0.f;
  uint2 v = *(const uint2*)(Min + (size_t)node * 64 + l16 * 4);  // self loop
  a0 = bfu2f(v.x & 0xffffu);
  a1 = bfu2f(v.x >> 16);
  a2 = bfu2f(v.y & 0xffffu);
  a3 = bfu2f(v.y >> 16);
  int start = (node == 0) ? 0 : rs[node - 1];
  int end = rs[node];
  int j = start;
  for (; j + 3 < end; j += 4) {
    int s0 = csr[j], s1 = csr[j + 1], s2 = csr[j + 2], s3 = csr[j + 3];
    uint2 u0 = *(const uint2*)(Min + (size_t)s0 * 64 + l16 * 4);
    uint2 u1 = *(const uint2*)(Min + (size_t)s1 * 64 + l16 * 4);
    uint2 u2 = *(const uint2*)(Min + (size_t)s2 * 64 + l16 * 4);
    uint2 u3 = *(const uint2*)(Min + (size_t)s3 * 64 + l16 * 4);
    ACC4(a0, a1, a2, a3, u0);
    ACC4(b0, b1, b2, b3, u1);
    ACC4(c0, c1, c2, c3, u2);
    ACC4(d0, d1, d2, d3, u3);
  }
  if (j + 1 < end) {
    int s0 = csr[j], s1 = csr[j + 1];
    uint2 u0 = *(const uint2*)(Min + (size_t)s0 * 64 + l16 * 4);
    uint2 u1 = *(const uint2*)(Min + (size_t)s1 * 64 + l16 * 4);
    ACC4(a0, a1, a2, a3, u0);
    ACC4(b0, b1, b2, b3, u1);
    j += 2;
  }
  if (j < end) {
    uint2 u0 = *(const uint2*)(Min + (size_t)csr[j] * 64 + l16 * 4);
    ACC4(a0, a1, a2, a3, u0);
  }
  A0 = (a0 + b0) + (c0 + d0);
  A1 = (a1 + b1) + (c1 + d1);
  A2 = (a2 + b2) + (c2 + d2);
  A3 = (a3 + b3) + (c3 + d3);
}

// ===== fused gather+act+MFMA: Mout = dis * (relu((agg Min)*dis + b) @ W) ====
__global__ __launch_bounds__(256) void k_gmm(
    const int* __restrict__ rs, const int* __restrict__ csr,
    const unsigned short* __restrict__ Min, const float* __restrict__ dis,
    const float* __restrict__ bias, const float* __restrict__ W,
    unsigned short* __restrict__ Mout, int n) {
  __shared__ __align__(16) unsigned short As[64 * 64];
  __shared__ __align__(16) unsigned short Bt[64 * 64];
  const int tid = threadIdx.x;
  const int bm = blockIdx.x * 64;
  // ---- stage Bt[n][k] = W[k][n] bf16, swizzled
  {
    int nn = tid & 63, k0 = (tid >> 6) * 16;
    bf16x8 v0, v1;
#pragma unroll
    for (int i = 0; i < 8; ++i) v0[i] = (short)f2bfu(W[(size_t)(k0 + i) * 64 + nn]);
#pragma unroll
    for (int i = 0; i < 8; ++i) v1[i] = (short)f2bfu(W[(size_t)(k0 + 8 + i) * 64 + nn]);
    int off0 = (nn * 128 + k0 * 2) ^ ((nn & 7) << 4);
    int off1 = (nn * 128 + (k0 + 8) * 2) ^ ((nn & 7) << 4);
    *(bf16x8*)((char*)Bt + off0) = v0;
    *(bf16x8*)((char*)Bt + off1) = v1;
  }
  // ---- gather + act into As
  const int lane = tid & 63;
  const int wv = tid >> 6;
  const int grp = lane >> 4, l16 = lane & 15;
  const float4 bb = *(const float4*)(bias + l16 * 4);
  for (int p = 0; p < 4; ++p) {
    int local = wv * 16 + p * 4 + grp;
    int node = bm + local;
    float A0 = 0.f, A1 = 0.f, A2 = 0.f, A3 = 0.f, dv = 0.f;
    if (node < n) {
      gather_rows(rs, csr, Min, node, l16, A0, A1, A2, A3);
      dv = dis[node];
    }
    ushort4 h;
    h.x = f2bfu(fmaxf(fmaf(A0, dv, bb.x), 0.f));
    h.y = f2bfu(fmaxf(fmaf(A1, dv, bb.y), 0.f));
    h.z = f2bfu(fmaxf(fmaf(A2, dv, bb.z), 0.f));
    h.w = f2bfu(fmaxf(fmaf(A3, dv, bb.w), 0.f));
    int off = (local * 128 + l16 * 8) ^ ((local & 7) << 4);
    *(ushort4*)((char*)As + off) = h;
  }
  __syncthreads();
  // ---- MFMA phase
  const int kb = lane >> 4, fr = lane & 15;
  f32x4 acc[4];
#pragma unroll
  for (int i = 0; i < 4; ++i) acc[i] = f32x4{0.f, 0.f, 0.f, 0.f};
  const int ar = wv * 16 + fr;
#pragma unroll
  for (int kc = 0; kc < 2; ++kc) {
    int aoff = (ar * 128 + kc * 64 + kb * 16) ^ ((ar & 7) << 4);
    bf16x8 a = *(const bf16x8*)((char*)As + aoff);
#pragma unroll
    for (int ni = 0; ni < 4; ++ni) {
      int nr = ni * 16 + fr;
      int boff = (nr * 128 + kc * 64 + kb * 16) ^ ((nr & 7) << 4);
      bf16x8 b = *(const bf16x8*)((char*)Bt + boff);
      acc[ni] = __builtin_amdgcn_mfma_f32_16x16x32_bf16(a, b, acc[ni], 0, 0, 0);
    }
  }
#pragma unroll
  for (int r = 0; r < 4; ++r) {
    int row = bm + wv * 16 + kb * 4 + r;
    if (row < n) {
      float dvo = dis[row];
#pragma unroll
      for (int ni = 0; ni < 4; ++ni)
        Mout[(size_t)row * 64 + ni * 16 + fr] = f2bfu(acc[ni][r] * dvo);
    }
  }
}

// ==== fused final gather+act+pool: sums += relu((agg M)*dis + b3) per graph ==
// wave handles 8 consecutive nodes; lane = feature (full 128B row per edge).
__global__ void k_gpool(const int* __restrict__ rs, const int* __restrict__ csr,
                        const unsigned short* __restrict__ M, const float* __restrict__ dis,
                        const float* __restrict__ b3, const int* __restrict__ batch,
                        float* __restrict__ sums, float* __restrict__ cntf, int n) {
  int w = (int)((blockIdx.x * (long)blockDim.x + threadIdx.x) >> 6);
  int lane = threadIdx.x & 63;
  int r0 = w * 8;
  if (r0 >= n) return;
  float bl = b3[lane];
  int cur = batch[r0];
  float acc = 0.f, c = 0.f;
  for (int i = 0; i < 8; ++i) {
    int node = r0 + i;
    int start = (node == 0) ? 0 : rs[node - 1];
    int end = rs[node];
    float a0 = bfu2f(M[(size_t)node * 64 + lane]);  // self loop
    float a1 = 0.f, a2 = 0.f, a3 = 0.f;
    int j = start;
    for (; j + 3 < end; j += 4) {
      int s0 = csr[j], s1 = csr[j + 1], s2 = csr[j + 2], s3 = csr[j + 3];
      unsigned short u0 = M[(size_t)s0 * 64 + lane];
      unsigned short u1 = M[(size_t)s1 * 64 + lane];
      unsigned short u2 = M[(size_t)s2 * 64 + lane];
      unsigned short u3 = M[(size_t)s3 * 64 + lane];
      a0 += bfu2f(u0);
      a1 += bfu2f(u1);
      a2 += bfu2f(u2);
      a3 += bfu2f(u3);
    }
    if (j + 1 < end) {
      unsigned short u0 = M[(size_t)csr[j] * 64 + lane];
      unsigned short u1 = M[(size_t)csr[j + 1] * 64 + lane];
      a0 += bfu2f(u0);
      a1 += bfu2f(u1);
      j += 2;
    }
    if (j < end) a0 += bfu2f(M[(size_t)csr[j] * 64 + lane]);
    float h = fmaxf(fmaf((a0 + a1) + (a2 + a3), dis[node], bl), 0.f);
    int b = batch[node];
    if (b == cur) {
      acc += h;
      c += 1.f;
    } else {
      unsafeAtomicAdd(&sums[(size_t)cur * 64 + lane], acc);
      if (lane == 0) unsafeAtomicAdd(&cntf[cur], c);
      cur = b;
      acc = h;
      c = 1.f;
    }
  }
  unsafeAtomicAdd(&sums[(size_t)cur * 64 + lane], acc);
  if (lane == 0) unsafeAtomicAdd(&cntf[cur], c);
}

// ================= drug fc: relu((sums/cnt) @ Wd + bd), 64 -> 128 ===========
__global__ void k_drugfc(const float* __restrict__ sums, const float* __restrict__ cnt,
                         const float* __restrict__ W, const float* __restrict__ b,
                         float* __restrict__ out, int B) {
  __shared__ float ps[64];
  int row = blockIdx.x;
  int tid = threadIdx.x;
  float inv = 1.0f / fmaxf(cnt[row], 1.0f);
  if (tid < 64) ps[tid] = sums[(long)row * 64 + tid] * inv;
  __syncthreads();
  float acc = b[tid];
#pragma unroll 8
  for (int k = 0; k < 64; ++k) acc = fmaf(ps[k], W[k * 128 + tid], acc);
  out[(long)row * 128 + tid] = fmaxf(acc, 0.0f);
}

// ============ f32 [M x Kin] -> bf16 [M x ldout], zero-padded cols ===========
__global__ void k_cvt_bf16(const float* __restrict__ X, unsigned short* __restrict__ Y,
                           int Kin, int ldout) {
  int row = blockIdx.x;
  const float* xr = X + (size_t)row * Kin;
  unsigned short* yr = Y + (size_t)row * ldout;
  for (int j = threadIdx.x; j < ldout; j += 256)
    yr[j] = (j < Kin) ? f2bfu(xr[j]) : 0;
}

// ===== bf16 MFMA GEMM, (4*MR)x128 tile, BK=32, reg-prefetch double-buffer ==
// MR = rows per wave (16 or 32). A: [M x lda] bf16; W: [K x N] f32 row-guard.
template <int MR, bool SPLIT, typename OT>
__global__ __launch_bounds__(256, 2) void k_gemm2(
    const unsigned short* __restrict__ A, const float* __restrict__ W,
    const float* __restrict__ bias, OT* __restrict__ C,
    int Mrows, int N, int K, int lda, int nsteps, int chunkSteps) {
  constexpr int NF = MR / 16;   // A frags per wave
  constexpr int BM = MR * 4;    // block rows
  __shared__ __align__(16) unsigned short As[2][BM * 32];
  __shared__ __align__(16) unsigned short Bs[2][128 * 32];
  const int tid = threadIdx.x;
  const int lane = tid & 63;
  const int wid = tid >> 6;
  const int bm = blockIdx.x * BM;
  const int bn = blockIdx.y * 128;
  const int kb = lane >> 4, fr = lane & 15;
  const int ss0 = blockIdx.z * chunkSteps;
  const int ss1 = min(nsteps, ss0 + chunkSteps);

  f32x4 acc[NF][8];
#pragma unroll
  for (int mi = 0; mi < NF; ++mi)
#pragma unroll
    for (int j = 0; j < 8; ++j) acc[mi][j] = f32x4{0.f, 0.f, 0.f, 0.f};

  int aOff[NF];
#pragma unroll
  for (int mi = 0; mi < NF; ++mi) {
    int ar = wid * MR + mi * 16 + fr;
    aOff[mi] = (ar * 64 + kb * 16) ^ ((ar & 7) << 4);
  }
  int bOff[8];
#pragma unroll
  for (int ni = 0; ni < 8; ++ni) {
    int nr = ni * 16 + fr;
    bOff[ni] = (nr * 64 + kb * 16) ^ ((nr & 7) << 4);
  }
  // A staging: BM*4 chunks of 16B; thread handles chunks {tid + p*256}
  int aW[NF];
  const unsigned short* aptrs[NF];
#pragma unroll
  for (int p = 0; p < NF; ++p) {
    int ch = tid + p * 256;
    int arow = ch >> 2, ac = ch & 3;
    aW[p] = (arow * 64 + ac * 16) ^ ((arow & 7) << 4);
    aptrs[p] = A + (size_t)(bm + arow) * lda + ac * 8;
  }
  const int bn_ = tid & 127, bk0 = (tid >> 7) * 2;
  int bW[2];
#pragma unroll
  for (int p = 0; p < 2; ++p) {
    int kbb = bk0 + p;
    bW[p] = (bn_ * 64 + kbb * 16) ^ ((bn_ & 7) << 4);
  }

  bf16x8 pa[NF];
  float pb[2][8];

#define LOAD_STEP(S)                                              \
  {                                                               \
    int k0 = (S) * 32;                                            \
    _Pragma("unroll") for (int p = 0; p < NF; ++p)                \
        pa[p] = *(const bf16x8*)(aptrs[p] + k0);                  \
    _Pragma("unroll") for (int p = 0; p < 2; ++p) {               \
      _Pragma("unroll") for (int i = 0; i < 8; ++i) {             \
        int gk = k0 + (bk0 + p) * 8 + i;                          \
        pb[p][i] = (gk < K) ? W[(size_t)gk * N + bn + bn_] : 0.f; \
      }                                                           \
    }                                                             \
  }
#define STORE_STEP(BUF)                                           \
  {                                                               \
    _Pragma("unroll") for (int p = 0; p < NF; ++p)                \
        *(bf16x8*)((char*)As[BUF] + aW[p]) = pa[p];               \
    _Pragma("unroll") for (int p = 0; p < 2; ++p) {               \
      bf16x8 v;                                                   \
      _Pragma("unroll") for (int i = 0; i < 8; ++i)               \
          v[i] = (short)f2bfu(pb[p][i]);                          \
      *(bf16x8*)((char*)Bs[BUF] + bW[p]) = v;                     \
    }                                                             \
  }

  LOAD_STEP(ss0);
  STORE_STEP(0);
  __syncthreads();
  int cur = 0;
  for (int s = ss0; s < ss1; ++s) {
    bool more = (s + 1 < ss1);
    if (more) LOAD_STEP(s + 1);
    bf16x8 a0[NF];
#pragma unroll
    for (int mi = 0; mi < NF; ++mi)
      a0[mi] = *(const bf16x8*)((char*)As[cur] + aOff[mi]);
#pragma unroll
    for (int ni = 0; ni < 8; ++ni) {
      bf16x8 b = *(const bf16x8*)((char*)Bs[cur] + bOff[ni]);
#pragma unroll
      for (int mi = 0; mi < NF; ++mi)
        acc[mi][ni] = __builtin_amdgcn_mfma_f32_16x16x32_bf16(a0[mi], b, acc[mi][ni], 0, 0, 0);
    }
    if (more) {
      STORE_STEP(cur ^ 1);
      __syncthreads();
      cur ^= 1;
    }
  }
  if constexpr (SPLIT) {
    float* Cz = (float*)C + (size_t)blockIdx.z * Mrows * N;
#pragma unroll
    for (int mi = 0; mi < NF; ++mi)
#pragma unroll
      for (int ni = 0; ni < 8; ++ni)
#pragma unroll
        for (int r = 0; r < 4; ++r) {
          int row = bm + wid * MR + mi * 16 + kb * 4 + r;
          int col = bn + ni * 16 + fr;
          Cz[(size_t)row * N + col] = acc[mi][ni][r];
        }
  } else {
    float bv[8];
#pragma unroll
    for (int ni = 0; ni < 8; ++ni) bv[ni] = bias[bn + ni * 16 + fr];
#pragma unroll
    for (int mi = 0; mi < NF; ++mi)
#pragma unroll
      for (int ni = 0; ni < 8; ++ni)
#pragma unroll
        for (int r = 0; r < 4; ++r) {
          int row = bm + wid * MR + mi * 16 + kb * 4 + r;
          int col = bn + ni * 16 + fr;
          float x = fmaxf(acc[mi][ni][r] + bv[ni], 0.f);
          if constexpr (__hip_internal::is_same<OT, float>::value) {
            C[(size_t)row * N + col] = x;
          } else {
            C[(size_t)row * N + col] = f2bfu(x);
          }
        }
  }
#undef LOAD_STEP
#undef STORE_STEP
}

// ---- concat + LayerNorm; prot = relu(sum of 4 K-split partials + bp) -------
__global__ void k_concat_ln(const float* __restrict__ drug, const float* __restrict__ protP,
                            const float* __restrict__ bp, const float* __restrict__ fpp,
                            unsigned short* __restrict__ comb, int B) {
  __shared__ float buf[CONCAT_F];
  __shared__ float rs[4], rs2[4];
  int row = blockIdx.x;
  int tid = threadIdx.x;
  const size_t MN = (size_t)B * 128;
  float s = 0.0f, s2 = 0.0f;
  for (int j = tid; j < CONCAT_F; j += 256) {
    float v;
    if (j < 128) {
      v = drug[(long)row * 128 + j];
    } else if (j < 256) {
      int c = j - 128;
      size_t o = (size_t)row * 128 + c;
      float acc = protP[o] + protP[MN + o] + protP[2 * MN + o] + protP[3 * MN + o];
      v = fmaxf(acc + bp[c], 0.0f);
    } else {
      v = fpp[(long)row * 881 + (j - 256)];
    }
    buf[j] = v;
    s += v;
    s2 += v * v;
  }
  for (int o = 32; o; o >>= 1) {
    s += __shfl_down(s, o, 64);
    s2 += __shfl_down(s2, o, 64);
  }
  int lane = tid & 63, wid = tid >> 6;
  if (lane == 0) { rs[wid] = s; rs2[wid] = s2; }
  __syncthreads();
  if (tid == 0) {
    float ts = rs[0] + rs[1] + rs[2] + rs[3];
    float ts2 = rs2[0] + rs2[1] + rs2[2] + rs2[3];
    float mu = ts / (float)CONCAT_F;
    float var = ts2 / (float)CONCAT_F - mu * mu;
    rs[0] = mu;
    rs2[0] = rsqrtf(fmaxf(var, 0.0f) + 1e-5f);
  }
  __syncthreads();
  float mu = rs[0], inv = rs2[0];
  for (int j = tid; j < CONCAT_P; j += 256) {
    unsigned short o = (j < CONCAT_F) ? f2bfu((buf[j] - mu) * inv) : 0;
    comb[(long)row * CONCAT_P + j] = o;
  }
}

// ---------------- fc3: X @ w + b, 256 -> 1 ----------------------------------
__global__ void k_fc3(const float* __restrict__ X, const float* __restrict__ W,
                      const float* __restrict__ bias, float* __restrict__ out, int B) {
  int w = (int)((blockIdx.x * (long)blockDim.x + threadIdx.x) >> 6);
  int lane = threadIdx.x & 63;
  if (w >= B) return;
  float s = 0.0f;
#pragma unroll
  for (int j = 0; j < 4; ++j) s = fmaf(X[(long)w * 256 + lane + j * 64], W[lane + j * 64], s);
  for (int o = 32; o; o >>= 1) s += __shfl_down(s, o, 64);
  if (lane == 0) out[w] = s + bias[0];
}

// ---------------------------------------------------------------------------
extern "C" void kernel_launch(void* const* d_in, const int* in_sizes, int n_in,
                              void* d_out, int out_size, void* d_ws, size_t ws_size,
                              hipStream_t stream) {
  const float* drug_x = (const float*)d_in[0];
  const int* ei = (const int*)d_in[1];
  const int* batch = (const int*)d_in[2];
  const float* protein_x = (const float*)d_in[3];
  const float* fpp = (const float*)d_in[4];
  const float* W1 = (const float*)d_in[5];
  const float* b1 = (const float*)d_in[6];
  const float* W2 = (const float*)d_in[7];
  const float* b2 = (const float*)d_in[8];
  const float* W3 = (const float*)d_in[9];
  const float* b3 = (const float*)d_in[10];
  const float* Wd = (const float*)d_in[11];
  const float* bd = (const float*)d_in[12];
  const float* Wp = (const float*)d_in[13];
  const float* bp = (const float*)d_in[14];
  const float* Wf1 = (const float*)d_in[15];
  const float* bf1 = (const float*)d_in[16];
  const float* Wf2 = (const float*)d_in[17];
  const float* bf2 = (const float*)d_in[18];
  const float* Wf3 = (const float*)d_in[19];
  const float* bf3 = (const float*)d_in[20];
  float* out = (float*)d_out;

  const int N = in_sizes[0] / 30;
  const int E = in_sizes[1] / 2;
  const int B = in_sizes[4] / 881;

  // ---- GCN-phase workspace (4-byte words) ----
  int* rs = (int*)d_ws;
  float* dis = (float*)d_ws + ((size_t)N + 1);
  int* csr = (int*)d_ws + (2 * (size_t)N + 1);
  size_t oM = 2 * (size_t)N + 2 + (size_t)E;
  unsigned short* M = (unsigned short*)((float*)d_ws + oM);
  unsigned short* H = M + (size_t)N * 64;
  float* sums = (float*)d_ws + (oM + 64 * (size_t)N);
  float* cntf = sums + (size_t)B * 64;
  int* part = (int*)(cntf + B);
  unsigned short* protbh = (unsigned short*)(part + 1024);  // B*PROT_P bf16
  // ---- dense-tail aliases at offset 0 (GCN buffers dead by then) ----
  float* tail = (float*)d_ws;
  float* drug = tail;                                        // B*128 f32
  float* protP = drug + (size_t)B * 128;                     // 4*B*128 f32 partials
  unsigned short* combh = (unsigned short*)(protP + 4 * (size_t)B * 128);  // B*1152 bf16
  unsigned short* act1h = combh + (size_t)B * CONCAT_P;      // B*512 bf16
  float* act2 = (float*)(act1h + (size_t)B * 512);           // B*256 f32

  const int* srcIdx = ei;
  const int* dstIdx = ei + E;

  // node-class shift: (N-1)>>shift <= 7  -> 8 contiguous node ranges
  int shift = 0;
  while (((N - 1) >> shift) > 7) ++shift;
  const int CHUNK = 2048;
  int G = (E + CHUNK - 1) / CHUNK;

  // ---- protein f32 -> bf16 ----
  k_cvt_bf16<<<B, 256, 0, stream>>>(protein_x, protbh, PROT_K, PROT_P);

  // ---- CSR build + degree (XCD-partitioned count/scatter) ----
  hipMemsetAsync(rs, 0, ((size_t)N + 1) * sizeof(int), stream);
  k_count_xcd<<<8 * G, 256, 0, stream>>>(dstIdx, rs, E, shift, CHUNK);
  int NB = (N + 1023) / 1024;
  k_scan_p1<<<NB, 256, 0, stream>>>(rs, part, dis, N);  // + dis
  k_scan_p2<<<1, 1024, 0, stream>>>(part, NB);
  k_scan_p3<<<NB, 256, 0, stream>>>(rs, part, N);
  k_scatter_xcd<<<8 * G, 256, 0, stream>>>(srcIdx, dstIdx, rs, csr, E, shift, CHUNK);

  // ---- GCN layers ----
  int mmBlocks = (N + 63) / 64;
  k_mm<30, false><<<mmBlocks, 256, 0, stream>>>(drug_x, W1, nullptr, dis, M, N);
  k_gmm<<<mmBlocks, 256, 0, stream>>>(rs, csr, M, dis, b1, W2, H, N);  // H = M2
  k_gmm<<<mmBlocks, 256, 0, stream>>>(rs, csr, H, dis, b2, W3, M, N);  // M = M3

  // ---- fused final gather + act + mean pool ----
  hipMemsetAsync(sums, 0, ((size_t)B * 64 + B) * sizeof(float), stream);
  int poolWaves = (N + 7) / 8;
  k_gpool<<<(poolWaves + 3) / 4, 256, 0, stream>>>(rs, csr, M, dis, b3, batch, sums, cntf, N);

  // ---- dense tail ----
  k_drugfc<<<B, 128, 0, stream>>>(sums, cntf, Wd, bd, drug, B);
  k_gemm2<16, true, float><<<dim3(B / 64, 1, 4), 256, 0, stream>>>(
      protbh, Wp, nullptr, protP, B, 128, PROT_K, PROT_P, 31, 8);
  k_concat_ln<<<B, 256, 0, stream>>>(drug, protP, bp, fpp, combh, B);
  k_gemm2<32, false, unsigned short><<<dim3(B / 128, 4, 1), 256, 0, stream>>>(
      combh, Wf1, bf1, act1h, B, 512, CONCAT_F, CONCAT_P, 36, 36);
  k_gemm2<16, false, float><<<dim3(B / 64, 2, 1), 256, 0, stream>>>(
      act1h, Wf2, bf2, act2, B, 256, 512, 512, 16, 16);
  k_fc3<<<(B + 3) / 4, 256, 0, stream>>>(act2, Wf3, bf3, out, B);
}